// Round 8
// baseline (386.840 us; speedup 1.0000x reference)
//
#include <hip/hip_runtime.h>
#include <hip/hip_cooperative_groups.h>
#include <math.h>

namespace cg = cooperative_groups;

#define N_G   64
#define M_N   32
#define FEAT  256
#define POSD  6
#define D     262
#define MSG   128
#define NCLS  7

#define KHW   288       // weight K window over h (262 -> 288)
#define KFULL 416       // full concat K [mv 128 | h 288]
#define HSTR  416       // G_H row stride (shorts): [mv 128 | h 262 | pad 26]
#define PSTR  320       // G_PA/G_PB row stride (shorts)

// workspace float offsets — packed weights then staged activations
#define O_WPROJ 0u
#define O_WMSG  76032u
#define O_WRZ   94464u
#define O_WXN   207616u
#define O_WHN   225024u
#define O_WRO   264192u
#define O_WRO2  282624u
#define O_GB    283648u      // 1088 fp32 gate biases
#define O_GHA   284736u      // [64][32][416] bf16  h-state buf A
#define O_GHB   710720u      // [64][32][416] bf16  h-state buf B
#define O_GPA   1136704u     // [64][32][320] bf16  proj-a
#define O_GPB   1464384u     // [64][32][320] bf16  proj-b
#define O_GATT  1792064u     // [64][32][40]  bf16  att (A-layout for mix)
#define O_GMSG  1833024u     // [64][128][40] bf16  msg0 (B^T layout)
#define O_B1P   1996864u     // [320] f32 padded link_b1
#define O_W2P   1997184u     // [320] f32 padded link_w2

typedef __attribute__((ext_vector_type(8))) short short8;
typedef __attribute__((ext_vector_type(4))) short short4v;
typedef __attribute__((ext_vector_type(4))) float floatx4;

#define MFMA __builtin_amdgcn_mfma_f32_16x16x32_bf16

__device__ __forceinline__ short f2bf(float f) {
    union { float f; unsigned u; } v; v.f = f;
    unsigned r = v.u + 0x7FFF + ((v.u >> 16) & 1);   // RNE
    return (short)(r >> 16);
}
__device__ __forceinline__ float bf2f(short s) {
    union { float f; unsigned u; } v;
    v.u = ((unsigned)(unsigned short)s) << 16;
    return v.f;
}
__device__ __forceinline__ float sigf(float x) {
    return __builtin_amdgcn_rcpf(1.f + __expf(-x));
}
__device__ __forceinline__ float tanh_fast(float x) {
    float e = __expf(-2.f * fabsf(x));
    float t = (1.f - e) * __builtin_amdgcn_rcpf(1.f + e);
    return copysignf(t, x);
}

// ---------------------------------------------------------------------------
// GRU tile phase: 1088 tile-waves (64 graphs x 17 d-tiles) over 1024 waves.
// ---------------------------------------------------------------------------
__device__ __forceinline__ void gru_phase(float* __restrict__ ws,
                                          const int* __restrict__ nrec_g,
                                          const int srcA, const int gwave,
                                          const int quad, const int lrow)
{
    const short* src = (const short*)(ws + (srcA ? O_GHA : O_GHB));
    short* dst       = (short*)(ws + (srcA ? O_GHB : O_GHA));
    const short* Wrz = (const short*)(ws + O_WRZ);
    const short* Wxn = (const short*)(ws + O_WXN);
    const short* Whn = (const short*)(ws + O_WHN);
    const float* gb  = ws + O_GB;

    for (int job = gwave; job < 1088; job += 1024) {
        const int b = job / 17, s = job % 17;
        const int nr = nrec_g[b];

        const short* ap0 = src + (size_t)(b * 32 + lrow) * HSTR + quad * 8;
        const short* ap1 = ap0 + 16 * HSTR;
        short8 aA0[13], aA1[13];
#pragma unroll
        for (int kk = 0; kk < 13; ++kk) {
            aA0[kk] = *(const short8*)(ap0 + kk * 32);
            aA1[kk] = *(const short8*)(ap1 + kk * 32);
        }
        const short* bpr = Wrz + (s * 16 + lrow) * KFULL + quad * 8;
        const short* bpz = bpr + 272 * KFULL;
        const short* bpx = Wxn + (s * 16 + lrow) * 128 + quad * 8;
        const short* bph = Whn + (s * 16 + lrow) * KHW + quad * 8;

        short8 wr[13];
#pragma unroll
        for (int kk = 0; kk < 13; ++kk) wr[kk] = *(const short8*)(bpr + kk * 32);

        floatx4 aR0 = {}, aR1 = {}, aZ0 = {}, aZ1 = {};
        floatx4 aN0 = {}, aN1 = {}, aH0 = {}, aH1 = {};
#pragma unroll
        for (int kk = 0; kk < 13; ++kk) {           // r (+x inline); stage z
            aR0 = MFMA(aA0[kk], wr[kk], aR0, 0, 0, 0);
            aR1 = MFMA(aA1[kk], wr[kk], aR1, 0, 0, 0);
            if (kk < 4) {
                short8 bx = *(const short8*)(bpx + kk * 32);
                aN0 = MFMA(aA0[kk], bx, aN0, 0, 0, 0);
                aN1 = MFMA(aA1[kk], bx, aN1, 0, 0, 0);
            }
            wr[kk] = *(const short8*)(bpz + kk * 32);
        }
#pragma unroll
        for (int kk = 0; kk < 13; ++kk) {           // z chain; stage h
            aZ0 = MFMA(aA0[kk], wr[kk], aZ0, 0, 0, 0);
            aZ1 = MFMA(aA1[kk], wr[kk], aZ1, 0, 0, 0);
            if (kk < 9) wr[kk] = *(const short8*)(bph + kk * 32);
        }
#pragma unroll
        for (int kk = 0; kk < 9; ++kk) {            // h chain
            aH0 = MFMA(aA0[kk + 4], wr[kk], aH0, 0, 0, 0);
            aH1 = MFMA(aA1[kk + 4], wr[kk], aH1, 0, 0, 0);
        }

        const int d = s * 16 + lrow;
        if (d < D) {
            float bgr = gb[d], bgz = gb[272 + d];
            float bxv = gb[544 + d], bhv = gb[816 + d];
#pragma unroll
            for (int i = 0; i < 2; ++i) {
                floatx4 vR = i ? aR1 : aR0, vZ = i ? aZ1 : aZ0;
                floatx4 vN = i ? aN1 : aN0, vH = i ? aH1 : aH0;
#pragma unroll
                for (int rr = 0; rr < 4; ++rr) {
                    int m = i * 16 + quad * 4 + rr;
                    float rg = sigf(vR[rr] + bgr);
                    float zg = sigf(vZ[rr] + bgz);
                    float cg = tanh_fast(vN[rr] + bxv + rg * (vH[rr] + bhv));
                    float hold = bf2f(src[(size_t)(b * 32 + m) * HSTR + 128 + d]);
                    float hv = (1.f - zg) * cg + zg * hold;
                    if (m >= nr) hv = 0.f;
                    dst[(size_t)(b * 32 + m) * HSTR + 128 + d] = f2bf(hv);
                }
            }
        }
    }
}

// ---------------------------------------------------------------------------
// Cooperative full-forward: 256 blocks x 256 threads, 7 grid.sync()s replace
// 7 kernel launches (R7 proved phase-split work is small but 8 launches cost
// ~5-8us each; grid.sync is ~1-3us). One block/CU guaranteed; (256,1) launch
// bounds -> VGPR ceiling 512, no spill risk for the staged GRU.
// ---------------------------------------------------------------------------
__global__ __launch_bounds__(256, 1) void coop_kernel(
    const float* __restrict__ nodes, const float* __restrict__ pos,
    const int* __restrict__ nrec_g,
    const float* __restrict__ w1, const float* __restrict__ b1g,
    const float* __restrict__ w2g, const float* __restrict__ b2g,
    const float* __restrict__ msg_w, const float* __restrict__ msg_bg,
    const float* __restrict__ w_ih, const float* __restrict__ w_hh,
    const float* __restrict__ b_ih, const float* __restrict__ b_hh,
    const float* __restrict__ ro_w1, const float* __restrict__ ro_b1g,
    const float* __restrict__ ro_w2, const float* __restrict__ ro_b2g,
    float* __restrict__ ws, float* __restrict__ att_out, float* __restrict__ pred)
{
    cg::grid_group grid = cg::this_grid();
    __shared__ __align__(16) short shmem[128 * 40];   // msgT (P5) / hidL (P7)

    const int tid = threadIdx.x;
    const int wave = tid >> 6, lane = tid & 63;
    const int quad = lane >> 4, lrow = lane & 15;
    const int gwave = blockIdx.x * 4 + wave;          // 0..1023

    // ================= P0: prep (weights, biases, h0, pads) =================
    for (int row0 = gwave; row0 < 5989; row0 += 1024) {
        int row = row0;
        if (row < 528) {                              // wproj [528][288]
            const int n = row;
            short* out = (short*)(ws + O_WPROJ) + n * 288;
            const float* src = (n < D) ? (w1 + n * 524) : (w1 + (n - D) * 524 + D);
            for (int k = lane; k < 288; k += 64)
                out[k] = f2bf((k < D && n < 524) ? src[k] : 0.f);
            continue;
        }
        row -= 528;
        if (row < 128) {                              // wmsg [128][288]
            short* out = (short*)(ws + O_WMSG) + row * 288;
            const float* src = msg_w + row * D;
            for (int k = lane; k < 288; k += 64)
                out[k] = f2bf(k < D ? src[k] : 0.f);
            continue;
        }
        row -= 128;
        if (row < 544) {                              // wrz [544][416]
            const int g = row;
            const int gi = (g < 272) ? 0 : 1;
            const int d = g - gi * 272;
            short* out = (short*)(ws + O_WRZ) + g * 416;
            if (d < D) {
                const int r = gi * D + d;
                const float* sih = w_ih + r * MSG;
                const float* shh = w_hh + r * D - 128;
                for (int k = lane; k < 416; k += 64) {
                    float v;
                    if (k < 128)            v = sih[k];
                    else if (k < 128 + D)   v = shh[k];
                    else                    v = 0.f;
                    out[k] = f2bf(v);
                }
            } else {
                for (int k = lane; k < 416; k += 64) out[k] = 0;
            }
            continue;
        }
        row -= 544;
        if (row < 272) {                              // wxn [272][128]
            const int d = row;
            short* out = (short*)(ws + O_WXN) + d * 128;
            const float* src = w_ih + (2 * D + d) * MSG;
            for (int k = lane; k < 128; k += 64)
                out[k] = f2bf(d < D ? src[k] : 0.f);
            continue;
        }
        row -= 272;
        if (row < 272) {                              // whn [272][288]
            const int d = row;
            short* out = (short*)(ws + O_WHN) + d * 288;
            const float* src = w_hh + (2 * D + d) * D;
            for (int k = lane; k < 288; k += 64)
                out[k] = f2bf((d < D && k < D) ? src[k] : 0.f);
            continue;
        }
        row -= 272;
        if (row < 128) {                              // wro [128][288]
            short* out = (short*)(ws + O_WRO) + row * 288;
            const float* src = ro_w1 + row * D;
            for (int k = lane; k < 288; k += 64)
                out[k] = f2bf(k < D ? src[k] : 0.f);
            continue;
        }
        row -= 128;
        if (row < 16) {                               // wro2 [16][128]
            short* out = (short*)(ws + O_WRO2) + row * 128;
            const float* src = ro_w2 + row * MSG;
            for (int k = lane; k < 128; k += 64)
                out[k] = f2bf(row < NCLS ? src[k] : 0.f);
            continue;
        }
        row -= 16;
        if (row < 4) {                                // gate biases [4][272]
            const int seg = row;
            float* out = ws + O_GB + seg * 272;
            for (int d = lane; d < 272; d += 64) {
                float v = 0.f;
                if (d < D) {
                    if (seg == 0)      v = b_ih[d] + b_hh[d];
                    else if (seg == 1) v = b_ih[D + d] + b_hh[D + d];
                    else if (seg == 2) v = b_ih[2 * D + d];
                    else               v = b_hh[2 * D + d];
                }
                out[d] = v;
            }
            continue;
        }
        row -= 4;
        if (row < 1) {                                // padded b1/w2 [320] f32
            float* b1p = ws + O_B1P;
            float* w2p = ws + O_W2P;
            for (int k = lane; k < 320; k += 64) {
                b1p[k] = (k < D) ? b1g[k] : 0.f;
                w2p[k] = (k < D) ? w2g[k] : 0.f;
            }
            continue;
        }
        row -= 1;
        if (row < 2048) {                             // h0 init -> G_HA h-part
            const int b = row >> 5, w = row & 31;
            short* out = (short*)(ws + O_GHA) + (size_t)(b * 32 + w) * HSTR + 128;
            const float* nsrc = nodes + (size_t)(b * 32 + w) * FEAT;
            const float* psrc = pos + (size_t)(b * 32 + w) * POSD;
            for (int k = lane; k < 288; k += 64) {
                float v = 0.f;
                if (k < FEAT)             v = nsrc[k];
                else if (k < FEAT + POSD) v = psrc[k - FEAT];
                out[k] = f2bf(v);
            }
            continue;
        }
        row -= 2048;
        {                                             // pad zeroing (2048 rows)
            const int b = row >> 5, w = row & 31;
            short* hb = (short*)(ws + O_GHB) + (size_t)(b * 32 + w) * HSTR + 128;
            short* pa = (short*)(ws + O_GPA) + (size_t)(b * 32 + w) * PSTR;
            short* pb = (short*)(ws + O_GPB) + (size_t)(b * 32 + w) * PSTR;
            if (lane < 26) hb[D + lane] = 0;
            if (lane < 58) { pa[D + lane] = 0; pb[D + lane] = 0; }
        }
    }
    grid.sync();

    // ================= P1: proj (0..32) + round-0 msg (33..40) ==============
    {
        const short* GH    = (const short*)(ws + O_GHA);
        short* GPA         = (short*)(ws + O_GPA);
        short* GPB         = (short*)(ws + O_GPB);
        short* GMSG        = (short*)(ws + O_GMSG);
        const short* Wproj = (const short*)(ws + O_WPROJ);
        const short* Wmsg  = (const short*)(ws + O_WMSG);

        for (int job = gwave; job < 2624; job += 1024) {
            const int b = job / 41, t = job % 41;
            const short* ap0 = GH + (size_t)(b * 32 + lrow) * HSTR + 128 + quad * 8;
            const short* ap1 = ap0 + 16 * HSTR;
            const short* bw = (t < 33)
                ? Wproj + (t * 16 + lrow) * KHW + quad * 8
                : Wmsg + ((t - 33) * 16 + lrow) * KHW + quad * 8;

            short8 a0[9], a1[9], wv[9];
#pragma unroll
            for (int kk = 0; kk < 9; ++kk) {
                a0[kk] = *(const short8*)(ap0 + kk * 32);
                a1[kk] = *(const short8*)(ap1 + kk * 32);
                wv[kk] = *(const short8*)(bw + kk * 32);
            }
            floatx4 acc0 = {}, acc1 = {};
#pragma unroll
            for (int kk = 0; kk < 9; ++kk) {
                acc0 = MFMA(a0[kk], wv[kk], acc0, 0, 0, 0);
                acc1 = MFMA(a1[kk], wv[kk], acc1, 0, 0, 0);
            }
            if (t < 33) {
                int col = t * 16 + lrow;
#pragma unroll
                for (int rr = 0; rr < 4; ++rr) {
                    int r0 = quad * 4 + rr;
                    if (col < D) {
                        GPA[(size_t)(b * 32 + r0) * PSTR + col] = f2bf(acc0[rr]);
                        GPA[(size_t)(b * 32 + r0 + 16) * PSTR + col] = f2bf(acc1[rr]);
                    } else if (col < 2 * D) {
                        GPB[(size_t)(b * 32 + r0) * PSTR + (col - D)] = f2bf(acc0[rr]);
                        GPB[(size_t)(b * 32 + r0 + 16) * PSTR + (col - D)] = f2bf(acc1[rr]);
                    }
                }
            } else {
                int col = (t - 33) * 16 + lrow;
                float bias = msg_bg[col];
#pragma unroll
                for (int rr = 0; rr < 4; ++rr) {
                    GMSG[(size_t)b * 5120 + col * 40 + quad * 4 + rr] = f2bf(acc0[rr] + bias);
                    GMSG[(size_t)b * 5120 + col * 40 + 16 + quad * 4 + rr] = f2bf(acc1[rr] + bias);
                }
            }
        }
    }
    grid.sync();

    // ================= P2: attention — 4096 16-lane groups ==================
    {
        const short* GPA = (const short*)(ws + O_GPA);
        const short* GPB = (const short*)(ws + O_GPB);
        short* GATT      = (short*)(ws + O_GATT);
        const float* b1p = ws + O_B1P;
        const float* w2p = ws + O_W2P;

        const int g = blockIdx.x * 16 + (tid >> 4);    // 0..4095
        const int b = g >> 6;
        const int rem = g & 63;
        const int i = rem >> 1, jh = (rem & 1) * 16;
        const int c16 = tid & 15;
        const int nr = nrec_g[b];
        const float b2v = b2g[0];

        float pav[5][4], b1v[5][4], w2v[5][4];
#pragma unroll
        for (int k = 0; k < 5; ++k) {
            int dbase = c16 * 4 + 64 * k;
            short4v p = *(const short4v*)(GPA + (size_t)(b * 32 + i) * PSTR + dbase);
            floatx4 bb = *(const floatx4*)(b1p + dbase);
            floatx4 ww = *(const floatx4*)(w2p + dbase);
#pragma unroll
            for (int e = 0; e < 4; ++e) {
                pav[k][e] = bf2f(p[e]); b1v[k][e] = bb[e]; w2v[k][e] = ww[e];
            }
        }
        float p0 = 0.f;
#pragma unroll
        for (int k = 0; k < 5; ++k)
#pragma unroll
            for (int e = 0; e < 4; ++e)
                p0 += fmaxf(b1v[k][e], 0.f) * w2v[k][e];
        p0 += __shfl_down(p0, 8, 16); p0 += __shfl_down(p0, 4, 16);
        p0 += __shfl_down(p0, 2, 16); p0 += __shfl_down(p0, 1, 16);
        float c0 = sigf(p0 + b2v);
        const bool vi = i < nr;
        for (int jj = 0; jj < 16; ++jj) {
            int j = jh + jj;
            float a;
            if (j < nr && vi) {
                const short* pb = GPB + (size_t)(b * 32 + j) * PSTR + c16 * 4;
                float s = 0.f;
#pragma unroll
                for (int k = 0; k < 5; ++k) {
                    short4v q = *(const short4v*)(pb + 64 * k);
#pragma unroll
                    for (int e = 0; e < 4; ++e) {
                        float v = pav[k][e] + bf2f(q[e]) + b1v[k][e];
                        s += fmaxf(v, 0.f) * w2v[k][e];
                    }
                }
                s += __shfl_down(s, 8, 16); s += __shfl_down(s, 4, 16);
                s += __shfl_down(s, 2, 16); s += __shfl_down(s, 1, 16);
                a = sigf(s + b2v);
            } else {
                a = c0;
            }
            if (c16 == 0) {
                att_out[((size_t)(b * 32 + i)) * 32 + j] = a;
                GATT[(size_t)b * 1280 + i * 40 + j] = f2bf((j < nr) ? a : 0.f);
            }
        }
    }
    grid.sync();

    // ================= P3: mix0 = att @ msg0 -> G_HA mv =====================
    if (gwave < 256) {
        const short* GATT = (const short*)(ws + O_GATT);
        const short* GMSG = (const short*)(ws + O_GMSG);
        short* GH         = (short*)(ws + O_GHA);
        const int b = gwave >> 2, ng = gwave & 3;

        short8 af0 = *(const short8*)(GATT + (size_t)b * 1280 + lrow * 40 + quad * 8);
        short8 af1 = *(const short8*)(GATT + (size_t)b * 1280 + (16 + lrow) * 40 + quad * 8);
        short8 bf0 = *(const short8*)(GMSG + (size_t)b * 5120 + (ng * 32 + lrow) * 40 + quad * 8);
        short8 bf1 = *(const short8*)(GMSG + (size_t)b * 5120 + (ng * 32 + 16 + lrow) * 40 + quad * 8);
        floatx4 c00 = {}, c01 = {}, c10 = {}, c11 = {};
        c00 = MFMA(af0, bf0, c00, 0, 0, 0);
        c01 = MFMA(af0, bf1, c01, 0, 0, 0);
        c10 = MFMA(af1, bf0, c10, 0, 0, 0);
        c11 = MFMA(af1, bf1, c11, 0, 0, 0);
#pragma unroll
        for (int rr = 0; rr < 4; ++rr) {
            int m0 = quad * 4 + rr;
            GH[(size_t)(b * 32 + m0) * HSTR + ng * 32 + lrow] = f2bf(c00[rr]);
            GH[(size_t)(b * 32 + m0) * HSTR + ng * 32 + 16 + lrow] = f2bf(c01[rr]);
            GH[(size_t)(b * 32 + m0 + 16) * HSTR + ng * 32 + lrow] = f2bf(c10[rr]);
            GH[(size_t)(b * 32 + m0 + 16) * HSTR + ng * 32 + 16 + lrow] = f2bf(c11[rr]);
        }
    }
    grid.sync();

    // ================= P4: GRU round 1 (G_HA -> G_HB) =======================
    gru_phase(ws, nrec_g, 1, gwave, quad, lrow);
    grid.sync();

    // ================= P5: msg1 (LDS) + mix1 -> G_HB mv (blocks 0..63) ======
    if (blockIdx.x < 64) {
        short* GHB        = (short*)(ws + O_GHB);
        const short* GATT = (const short*)(ws + O_GATT);
        const short* Wmsg = (const short*)(ws + O_WMSG);
        const int b = blockIdx.x;

        const short* ap0 = GHB + (size_t)(b * 32 + lrow) * HSTR + 128 + quad * 8;
        const short* ap1 = ap0 + 16 * HSTR;
        short8 a0[9], a1[9];
#pragma unroll
        for (int kk = 0; kk < 9; ++kk) {
            a0[kk] = *(const short8*)(ap0 + kk * 32);
            a1[kk] = *(const short8*)(ap1 + kk * 32);
        }
#pragma unroll
        for (int ti = 0; ti < 2; ++ti) {
            int s = wave + ti * 4;
            const short* bw = Wmsg + (s * 16 + lrow) * KHW + quad * 8;
            short8 wv[9];
#pragma unroll
            for (int kk = 0; kk < 9; ++kk) wv[kk] = *(const short8*)(bw + kk * 32);
            floatx4 acc0 = {}, acc1 = {};
#pragma unroll
            for (int kk = 0; kk < 9; ++kk) {
                acc0 = MFMA(a0[kk], wv[kk], acc0, 0, 0, 0);
                acc1 = MFMA(a1[kk], wv[kk], acc1, 0, 0, 0);
            }
            int col = s * 16 + lrow;
            float bias = msg_bg[col];
#pragma unroll
            for (int rr = 0; rr < 4; ++rr) {
                shmem[col * 40 + quad * 4 + rr] = f2bf(acc0[rr] + bias);
                shmem[col * 40 + 16 + quad * 4 + rr] = f2bf(acc1[rr] + bias);
            }
        }
        __syncthreads();
        {
            const int ng = wave;
            short8 af0 = *(const short8*)(GATT + (size_t)b * 1280 + lrow * 40 + quad * 8);
            short8 af1 = *(const short8*)(GATT + (size_t)b * 1280 + (16 + lrow) * 40 + quad * 8);
            short8 bf0 = *(const short8*)(shmem + (ng * 32 + lrow) * 40 + quad * 8);
            short8 bf1 = *(const short8*)(shmem + (ng * 32 + 16 + lrow) * 40 + quad * 8);
            floatx4 c00 = {}, c01 = {}, c10 = {}, c11 = {};
            c00 = MFMA(af0, bf0, c00, 0, 0, 0);
            c01 = MFMA(af0, bf1, c01, 0, 0, 0);
            c10 = MFMA(af1, bf0, c10, 0, 0, 0);
            c11 = MFMA(af1, bf1, c11, 0, 0, 0);
#pragma unroll
            for (int rr = 0; rr < 4; ++rr) {
                int m0 = quad * 4 + rr;
                GHB[(size_t)(b * 32 + m0) * HSTR + ng * 32 + lrow] = f2bf(c00[rr]);
                GHB[(size_t)(b * 32 + m0) * HSTR + ng * 32 + 16 + lrow] = f2bf(c01[rr]);
                GHB[(size_t)(b * 32 + m0 + 16) * HSTR + ng * 32 + lrow] = f2bf(c10[rr]);
                GHB[(size_t)(b * 32 + m0 + 16) * HSTR + ng * 32 + 16 + lrow] = f2bf(c11[rr]);
            }
        }
    }
    grid.sync();

    // ================= P6: GRU round 2 (G_HB -> G_HA) =======================
    gru_phase(ws, nrec_g, 0, gwave, quad, lrow);
    grid.sync();

    // ================= P7: readout + final (blocks 0..63) ===================
    if (blockIdx.x < 64) {
        const short* GHA  = (const short*)(ws + O_GHA);
        const short* Wro  = (const short*)(ws + O_WRO);
        const short* Wro2 = (const short*)(ws + O_WRO2);
        const int b = blockIdx.x;
        const int nr = nrec_g[b];

        const short* ap0 = GHA + (size_t)(b * 32 + lrow) * HSTR + 128 + quad * 8;
        const short* ap1 = ap0 + 16 * HSTR;
        short8 a0[9], a1[9];
#pragma unroll
        for (int kk = 0; kk < 9; ++kk) {
            a0[kk] = *(const short8*)(ap0 + kk * 32);
            a1[kk] = *(const short8*)(ap1 + kk * 32);
        }
#pragma unroll
        for (int ti = 0; ti < 2; ++ti) {
            int s = wave + ti * 4;
            const short* bw = Wro + (s * 16 + lrow) * KHW + quad * 8;
            short8 wv[9];
#pragma unroll
            for (int kk = 0; kk < 9; ++kk) wv[kk] = *(const short8*)(bw + kk * 32);
            floatx4 acc0 = {}, acc1 = {};
#pragma unroll
            for (int kk = 0; kk < 9; ++kk) {
                acc0 = MFMA(a0[kk], wv[kk], acc0, 0, 0, 0);
                acc1 = MFMA(a1[kk], wv[kk], acc1, 0, 0, 0);
            }
            int col = s * 16 + lrow;
            float bias = ro_b1g[col];
#pragma unroll
            for (int rr = 0; rr < 4; ++rr) {
                shmem[(quad * 4 + rr) * 136 + col] = f2bf(fmaxf(acc0[rr] + bias, 0.f));
                shmem[(16 + quad * 4 + rr) * 136 + col] = f2bf(fmaxf(acc1[rr] + bias, 0.f));
            }
        }
        __syncthreads();
        if (wave == 0) {
            const short* bw = Wro2 + lrow * 128 + quad * 8;
            short8 wv[4];
#pragma unroll
            for (int kk = 0; kk < 4; ++kk) wv[kk] = *(const short8*)(bw + kk * 32);
            floatx4 acc0 = {}, acc1 = {};
            const short* ap = shmem + lrow * 136 + quad * 8;
#pragma unroll
            for (int kk = 0; kk < 4; ++kk) {
                short8 x0 = *(const short8*)(ap + kk * 32);
                short8 x1 = *(const short8*)(ap + 16 * 136 + kk * 32);
                acc0 = MFMA(x0, wv[kk], acc0, 0, 0, 0);
                acc1 = MFMA(x1, wv[kk], acc1, 0, 0, 0);
            }
            int q = lrow;
            if (q < NCLS) {
                float bias = ro_b2g[q];
#pragma unroll
                for (int i = 0; i < 2; ++i) {
#pragma unroll
                    for (int rr = 0; rr < 4; ++rr) {
                        int m = i * 16 + quad * 4 + rr;
                        float v = (i ? acc1[rr] : acc0[rr]) + bias;
                        if (m >= nr) v = 0.f;
                        pred[((size_t)(b * 32 + m)) * NCLS + q] = v;
                    }
                }
            }
        }
    }
}

// ---------------------------------------------------------------------------
extern "C" void kernel_launch(void* const* d_in, const int* in_sizes, int n_in,
                              void* d_out, int out_size, void* d_ws, size_t ws_size,
                              hipStream_t stream)
{
    const float* nodes = (const float*)d_in[0];
    const float* pos   = (const float*)d_in[1];
    const int*   nrec  = (const int*)d_in[2];
    const float* w1    = (const float*)d_in[3];
    const float* b1    = (const float*)d_in[4];
    const float* w2    = (const float*)d_in[5];
    const float* b2    = (const float*)d_in[6];
    const float* msg_w = (const float*)d_in[7];
    const float* msg_b = (const float*)d_in[8];
    const float* w_ih  = (const float*)d_in[9];
    const float* w_hh  = (const float*)d_in[10];
    const float* b_ih  = (const float*)d_in[11];
    const float* b_hh  = (const float*)d_in[12];
    const float* ro_w1 = (const float*)d_in[13];
    const float* ro_b1 = (const float*)d_in[14];
    const float* ro_w2 = (const float*)d_in[15];
    const float* ro_b2 = (const float*)d_in[16];
    float* ws   = (float*)d_ws;
    float* pred = (float*)d_out;
    float* attout = pred + (size_t)N_G * M_N * NCLS;

    void* args[] = {
        (void*)&nodes, (void*)&pos, (void*)&nrec,
        (void*)&w1, (void*)&b1, (void*)&w2, (void*)&b2,
        (void*)&msg_w, (void*)&msg_b, (void*)&w_ih, (void*)&w_hh,
        (void*)&b_ih, (void*)&b_hh, (void*)&ro_w1, (void*)&ro_b1,
        (void*)&ro_w2, (void*)&ro_b2, (void*)&ws, (void*)&attout, (void*)&pred
    };
    hipLaunchCooperativeKernel((void*)coop_kernel, dim3(256), dim3(256),
                               args, 0, stream);
}

// Round 9
// 159.432 us; speedup vs baseline: 2.4264x; 2.4264x over previous
//
#include <hip/hip_runtime.h>
#include <math.h>

#define N_G   64
#define M_N   32
#define FEAT  256
#define POSD  6
#define D     262
#define MSG   128
#define NCLS  7

#define KA_S  424       // LDS buf row stride (shorts): [mv 128 | h 262 | pad]
#define KHW   288       // weight K window over h (262 -> 288)
#define KFULL 416       // full concat K [mv 128 | h 288]
#define HSTR  416       // G_H row stride (shorts): [mv 128 | h 262 | pad 26]
#define PSTR  320       // G_PA/G_PB row stride (shorts)

// workspace float offsets — packed weights then staged activations
#define O_WPROJ 0u
#define O_WMSG  76032u
#define O_WRZ   94464u
#define O_WXN   207616u
#define O_WHN   225024u
#define O_WRO   264192u
#define O_WRO2  282624u
#define O_GB    283648u      // 1088 fp32 gate biases
#define O_GHA   284736u      // [64][32][416] bf16  h0 (written by prep)
#define O_GPA   1136704u     // [64][32][320] bf16  proj-a
#define O_GPB   1464384u     // [64][32][320] bf16  proj-b
#define O_GATT  1792064u     // [64][32][40]  bf16  att (A-layout for mix)
#define O_GMSG  1833024u     // [64][128][40] bf16  msg0 (B^T layout)
#define O_B1P   1996864u     // [320] f32 padded link_b1
#define O_W2P   1997184u     // [320] f32 padded link_w2

typedef __attribute__((ext_vector_type(8))) short short8;
typedef __attribute__((ext_vector_type(4))) short short4v;
typedef __attribute__((ext_vector_type(4))) float floatx4;

#define MFMA __builtin_amdgcn_mfma_f32_16x16x32_bf16

__device__ __forceinline__ short f2bf(float f) {
    union { float f; unsigned u; } v; v.f = f;
    unsigned r = v.u + 0x7FFF + ((v.u >> 16) & 1);   // RNE
    return (short)(r >> 16);
}
__device__ __forceinline__ float bf2f(short s) {
    union { float f; unsigned u; } v;
    v.u = ((unsigned)(unsigned short)s) << 16;
    return v.f;
}
__device__ __forceinline__ float sigf(float x) {
    return __builtin_amdgcn_rcpf(1.f + __expf(-x));
}
__device__ __forceinline__ float tanh_fast(float x) {
    float e = __expf(-2.f * fabsf(x));
    float t = (1.f - e) * __builtin_amdgcn_rcpf(1.f + e);
    return copysignf(t, x);
}

// ---------------------------------------------------------------------------
// prep: row-per-wave weight pack + h0 init + padded b1/w2. (R7 version)
// ---------------------------------------------------------------------------
__global__ __launch_bounds__(256) void prep_kernel(
    const float* __restrict__ w1, const float* __restrict__ msg_w,
    const float* __restrict__ w_ih, const float* __restrict__ w_hh,
    const float* __restrict__ ro_w1, const float* __restrict__ ro_w2,
    const float* __restrict__ b_ih, const float* __restrict__ b_hh,
    const float* __restrict__ b1g, const float* __restrict__ w2g,
    const float* __restrict__ nodes, const float* __restrict__ pos,
    float* __restrict__ ws)
{
    int row = blockIdx.x * 4 + (threadIdx.x >> 6);
    const int lane = threadIdx.x & 63;
    if (row >= 3941) return;

    if (row < 528) {                              // wproj [528][288]
        const int n = row;
        short* out = (short*)(ws + O_WPROJ) + n * 288;
        const float* src = (n < D) ? (w1 + n * 524) : (w1 + (n - D) * 524 + D);
        for (int k = lane; k < 288; k += 64)
            out[k] = f2bf((k < D && n < 524) ? src[k] : 0.f);
        return;
    }
    row -= 528;
    if (row < 128) {                              // wmsg [128][288]
        short* out = (short*)(ws + O_WMSG) + row * 288;
        const float* src = msg_w + row * D;
        for (int k = lane; k < 288; k += 64)
            out[k] = f2bf(k < D ? src[k] : 0.f);
        return;
    }
    row -= 128;
    if (row < 544) {                              // wrz [544][416]
        const int g = row;
        const int gi = (g < 272) ? 0 : 1;
        const int d = g - gi * 272;
        short* out = (short*)(ws + O_WRZ) + g * 416;
        if (d < D) {
            const int r = gi * D + d;
            const float* sih = w_ih + r * MSG;
            const float* shh = w_hh + r * D - 128;
            for (int k = lane; k < 416; k += 64) {
                float v;
                if (k < 128)            v = sih[k];
                else if (k < 128 + D)   v = shh[k];
                else                    v = 0.f;
                out[k] = f2bf(v);
            }
        } else {
            for (int k = lane; k < 416; k += 64) out[k] = 0;
        }
        return;
    }
    row -= 544;
    if (row < 272) {                              // wxn [272][128]
        const int d = row;
        short* out = (short*)(ws + O_WXN) + d * 128;
        const float* src = w_ih + (2 * D + d) * MSG;
        for (int k = lane; k < 128; k += 64)
            out[k] = f2bf(d < D ? src[k] : 0.f);
        return;
    }
    row -= 272;
    if (row < 272) {                              // whn [272][288]
        const int d = row;
        short* out = (short*)(ws + O_WHN) + d * 288;
        const float* src = w_hh + (2 * D + d) * D;
        for (int k = lane; k < 288; k += 64)
            out[k] = f2bf((d < D && k < D) ? src[k] : 0.f);
        return;
    }
    row -= 272;
    if (row < 128) {                              // wro [128][288]
        short* out = (short*)(ws + O_WRO) + row * 288;
        const float* src = ro_w1 + row * D;
        for (int k = lane; k < 288; k += 64)
            out[k] = f2bf(k < D ? src[k] : 0.f);
        return;
    }
    row -= 128;
    if (row < 16) {                               // wro2 [16][128]
        short* out = (short*)(ws + O_WRO2) + row * 128;
        const float* src = ro_w2 + row * MSG;
        for (int k = lane; k < 128; k += 64)
            out[k] = f2bf(row < NCLS ? src[k] : 0.f);
        return;
    }
    row -= 16;
    if (row < 4) {                                // gate biases [4][272]
        const int seg = row;
        float* out = ws + O_GB + seg * 272;
        for (int d = lane; d < 272; d += 64) {
            float v = 0.f;
            if (d < D) {
                if (seg == 0)      v = b_ih[d] + b_hh[d];
                else if (seg == 1) v = b_ih[D + d] + b_hh[D + d];
                else if (seg == 2) v = b_ih[2 * D + d];
                else               v = b_hh[2 * D + d];
            }
            out[d] = v;
        }
        return;
    }
    row -= 4;
    if (row < 1) {                                // padded b1/w2 [320] f32
        float* b1p = ws + O_B1P;
        float* w2p = ws + O_W2P;
        for (int k = lane; k < 320; k += 64) {
            b1p[k] = (k < D) ? b1g[k] : 0.f;
            w2p[k] = (k < D) ? w2g[k] : 0.f;
        }
        return;
    }
    row -= 1;
    {                                             // h0 init -> G_HA h-part (2048)
        const int b = row >> 5, w = row & 31;
        short* out = (short*)(ws + O_GHA) + (size_t)(b * 32 + w) * HSTR + 128;
        const float* nsrc = nodes + (size_t)(b * 32 + w) * FEAT;
        const float* psrc = pos + (size_t)(b * 32 + w) * POSD;
        for (int k = lane; k < 288; k += 64) {
            float v = 0.f;
            if (k < FEAT)             v = nsrc[k];
            else if (k < FEAT + POSD) v = psrc[k - FEAT];
            out[k] = f2bf(v);
        }
    }
}

// ---------------------------------------------------------------------------
// k_proj: proj (tiles 0..32) + round-0 msg (33..40). 2624 tile-waves. (R7)
// ---------------------------------------------------------------------------
__global__ __launch_bounds__(256, 2) void k_proj(
    const float* __restrict__ ws, const float* __restrict__ msg_bg)
{
    const short* GH    = (const short*)(ws + O_GHA);
    short* GPA         = (short*)(ws + O_GPA);
    short* GPB         = (short*)(ws + O_GPB);
    short* GMSG        = (short*)(ws + O_GMSG);
    const short* Wproj = (const short*)(ws + O_WPROJ);
    const short* Wmsg  = (const short*)(ws + O_WMSG);

    const int job = blockIdx.x * 4 + (threadIdx.x >> 6);   // 656*4 = 2624 exact
    const int b = job / 41, t = job % 41;
    const int lane = threadIdx.x & 63;
    const int quad = lane >> 4, lrow = lane & 15;

    const short* ap0 = GH + (size_t)(b * 32 + lrow) * HSTR + 128 + quad * 8;
    const short* ap1 = ap0 + 16 * HSTR;
    const short* bw = (t < 33)
        ? Wproj + (t * 16 + lrow) * KHW + quad * 8
        : Wmsg + ((t - 33) * 16 + lrow) * KHW + quad * 8;

    short8 a0[9], a1[9], wv[9];
#pragma unroll
    for (int kk = 0; kk < 9; ++kk) {
        a0[kk] = *(const short8*)(ap0 + kk * 32);
        a1[kk] = *(const short8*)(ap1 + kk * 32);
        wv[kk] = *(const short8*)(bw + kk * 32);
    }
    floatx4 acc0 = {}, acc1 = {};
#pragma unroll
    for (int kk = 0; kk < 9; ++kk) {
        acc0 = MFMA(a0[kk], wv[kk], acc0, 0, 0, 0);
        acc1 = MFMA(a1[kk], wv[kk], acc1, 0, 0, 0);
    }
    if (t < 33) {
        int col = t * 16 + lrow;
#pragma unroll
        for (int rr = 0; rr < 4; ++rr) {
            int r0 = quad * 4 + rr;
            if (col < D) {
                GPA[(size_t)(b * 32 + r0) * PSTR + col] = f2bf(acc0[rr]);
                GPA[(size_t)(b * 32 + r0 + 16) * PSTR + col] = f2bf(acc1[rr]);
            } else if (col < 2 * D) {
                GPB[(size_t)(b * 32 + r0) * PSTR + (col - D)] = f2bf(acc0[rr]);
                GPB[(size_t)(b * 32 + r0 + 16) * PSTR + (col - D)] = f2bf(acc1[rr]);
            }
        }
    } else {
        int col = (t - 33) * 16 + lrow;
        float bias = msg_bg[col];
#pragma unroll
        for (int rr = 0; rr < 4; ++rr) {
            GMSG[(size_t)b * 5120 + col * 40 + quad * 4 + rr] = f2bf(acc0[rr] + bias);
            GMSG[(size_t)b * 5120 + col * 40 + 16 + quad * 4 + rr] = f2bf(acc1[rr] + bias);
        }
    }
}

// ---------------------------------------------------------------------------
// k_att: 4096 groups of 16 lanes: (graph, receiver i, j-half), 16 j's each. (R7)
// ---------------------------------------------------------------------------
__global__ __launch_bounds__(256, 4) void k_att(
    const float* __restrict__ ws, const int* __restrict__ nrec_g,
    const float* __restrict__ b2g, float* __restrict__ att_out)
{
    const short* GPA = (const short*)(ws + O_GPA);
    const short* GPB = (const short*)(ws + O_GPB);
    short* GATT      = (short*)(ws + O_GATT);
    const float* b1p = ws + O_B1P;
    const float* w2p = ws + O_W2P;

    const int g = blockIdx.x * 16 + (threadIdx.x >> 4);    // 0..4095
    const int b = g >> 6;
    const int rem = g & 63;
    const int i = rem >> 1, jh = (rem & 1) * 16;
    const int c16 = threadIdx.x & 15;
    const int nr = nrec_g[b];
    const float b2v = b2g[0];

    float pav[5][4], b1v[5][4], w2v[5][4];
#pragma unroll
    for (int k = 0; k < 5; ++k) {
        int dbase = c16 * 4 + 64 * k;
        short4v p = *(const short4v*)(GPA + (size_t)(b * 32 + i) * PSTR + dbase);
        floatx4 bb = *(const floatx4*)(b1p + dbase);
        floatx4 ww = *(const floatx4*)(w2p + dbase);
#pragma unroll
        for (int e = 0; e < 4; ++e) {
            pav[k][e] = bf2f(p[e]); b1v[k][e] = bb[e]; w2v[k][e] = ww[e];
        }
    }
    float p0 = 0.f;
#pragma unroll
    for (int k = 0; k < 5; ++k)
#pragma unroll
        for (int e = 0; e < 4; ++e)
            p0 += fmaxf(b1v[k][e], 0.f) * w2v[k][e];
    p0 += __shfl_down(p0, 8, 16); p0 += __shfl_down(p0, 4, 16);
    p0 += __shfl_down(p0, 2, 16); p0 += __shfl_down(p0, 1, 16);
    float c0 = sigf(p0 + b2v);
    const bool vi = i < nr;
    for (int jj = 0; jj < 16; ++jj) {
        int j = jh + jj;
        float a;
        if (j < nr && vi) {
            const short* pb = GPB + (size_t)(b * 32 + j) * PSTR + c16 * 4;
            float s = 0.f;
#pragma unroll
            for (int k = 0; k < 5; ++k) {
                short4v q = *(const short4v*)(pb + 64 * k);
#pragma unroll
                for (int e = 0; e < 4; ++e) {
                    float v = pav[k][e] + bf2f(q[e]) + b1v[k][e];
                    s += fmaxf(v, 0.f) * w2v[k][e];
                }
            }
            s += __shfl_down(s, 8, 16); s += __shfl_down(s, 4, 16);
            s += __shfl_down(s, 2, 16); s += __shfl_down(s, 1, 16);
            a = sigf(s + b2v);
        } else {
            a = c0;
        }
        if (c16 == 0) {
            att_out[((size_t)(b * 32 + i)) * 32 + j] = a;
            GATT[(size_t)b * 1280 + i * 40 + j] = f2bf((j < nr) ? a : 0.f);
        }
    }
}

// ---------------------------------------------------------------------------
// k_tail: per-graph fused tail (64 blocks x 512): stage -> mix0 -> GRU1 ->
// msg1+mix1 -> GRU2 -> readout -> final. Identical phase bodies to R6's
// best-measured fused kernel; P0-convert and P1 (the serial-heaviest phases)
// are gone — done full-chip by prep/k_proj.
// ---------------------------------------------------------------------------
__global__ __launch_bounds__(512, 2) void k_tail(
    float* __restrict__ ws, const int* __restrict__ nrec_g,
    const float* __restrict__ msg_bg, const float* __restrict__ ro_b1g,
    const float* __restrict__ ro_b2g, float* __restrict__ pred)
{
    const short* Wmsg = (const short*)(ws + O_WMSG);
    const short* Wrz  = (const short*)(ws + O_WRZ);
    const short* Wxn  = (const short*)(ws + O_WXN);
    const short* Whn  = (const short*)(ws + O_WHN);
    const short* Wro  = (const short*)(ws + O_WRO);
    const short* Wro2 = (const short*)(ws + O_WRO2);
    const float* gb   = ws + O_GB;

    __shared__ __align__(16) short bufA[32 * KA_S];
    __shared__ __align__(16) short bufB[32 * KA_S];
    __shared__ __align__(16) short attL[32 * 40];
    __shared__ __align__(16) short msgT[128 * 40];
    __shared__ __align__(16) short hidL[32 * 136];

    const int b = blockIdx.x;
    const int tid = threadIdx.x;
    const int wave = tid >> 6, lane = tid & 63;
    const int quad = lane >> 4, lrow = lane & 15;
    const int nr = nrec_g[b];

    // ---- L2 priming: touch Wrz/Wxn/Whn (contiguous ~663 KB) early ----
    floatx4 prm[10];
    {
        const floatx4* pb = (const floatx4*)(ws + O_WRZ);
        const int base = wave * 64 + lane;
#pragma unroll
        for (int p = 0; p < 10; ++p)
            prm[p] = pb[(p * 512 + base) * 8];      // 128 B stride
    }

    // ---- stage: h0 -> bufA, GATT -> attL, GMSG -> msgT, zero bufB h-pads ----
    {
        const short* GHA  = (const short*)(ws + O_GHA);
        const short* GATT = (const short*)(ws + O_GATT);
        const short* GMSG = (const short*)(ws + O_GMSG);
        for (int idx = tid; idx < 32 * 36; idx += 512) {       // h cols 128..415
            int w = idx / 36, c8 = idx % 36;
            *(short8*)(bufA + w * KA_S + 128 + c8 * 8) =
                *(const short8*)(GHA + (size_t)(b * 32 + w) * HSTR + 128 + c8 * 8);
        }
        for (int idx = tid; idx < 160; idx += 512)             // attL 1280 shorts
            *(short8*)(attL + idx * 8) =
                *(const short8*)(GATT + (size_t)b * 1280 + idx * 8);
        for (int idx = tid; idx < 640; idx += 512)             // msgT 5120 shorts
            *(short8*)(msgT + idx * 8) =
                *(const short8*)(GMSG + (size_t)b * 5120 + idx * 8);
        for (int idx = tid; idx < 32 * 26; idx += 512) {       // bufB h pads
            int w = idx / 26, c = idx % 26;
            bufB[w * KA_S + 390 + c] = 0;
        }
    }
#pragma unroll
    for (int p = 0; p < 10; ++p) asm volatile("" :: "v"(prm[p]));
    __syncthreads();

    // ---- two message-passing rounds (R6 bodies) ----
    for (int rnd = 0; rnd < 2; ++rnd) {
        short* src = rnd ? bufB : bufA;
        short* dst = rnd ? bufA : bufB;

        // msg = h @ Wmsg^T + msg_b -> msgT (round 0 precomputed by k_proj)
        if (rnd) {
            int s = wave;
            const short* bw = Wmsg + (s * 16 + lrow) * KHW + quad * 8;
            short8 wm[9];
#pragma unroll
            for (int kk = 0; kk < 9; ++kk) wm[kk] = *(const short8*)(bw + kk * 32);
            floatx4 acc0 = {}, acc1 = {};
            const short* ap = src + lrow * KA_S + 128 + quad * 8;
#pragma unroll
            for (int kk = 0; kk < 9; ++kk) {
                short8 x0 = *(const short8*)(ap + kk * 32);
                short8 x1 = *(const short8*)(ap + 16 * KA_S + kk * 32);
                acc0 = MFMA(x0, wm[kk], acc0, 0, 0, 0);
                acc1 = MFMA(x1, wm[kk], acc1, 0, 0, 0);
            }
            int col = s * 16 + lrow;
            float bias = msg_bg[col];
#pragma unroll
            for (int rr = 0; rr < 4; ++rr) {
                msgT[col * 40 + quad * 4 + rr] = f2bf(acc0[rr] + bias);
                msgT[col * 40 + 16 + quad * 4 + rr] = f2bf(acc1[rr] + bias);
            }
            __syncthreads();
        }

        // mix via MFMA: mv = attL(32x32) @ msg -> bf16 src cols 0..127
        {
            int mi = wave & 1, ng = wave >> 1;
            short8 afrag = *(const short8*)(attL + (mi * 16 + lrow) * 40 + quad * 8);
            floatx4 acc0 = {}, acc1 = {};
            short8 bf0 = *(const short8*)(msgT + (ng * 32 + lrow) * 40 + quad * 8);
            short8 bf1 = *(const short8*)(msgT + (ng * 32 + 16 + lrow) * 40 + quad * 8);
            acc0 = MFMA(afrag, bf0, acc0, 0, 0, 0);
            acc1 = MFMA(afrag, bf1, acc1, 0, 0, 0);
#pragma unroll
            for (int rr = 0; rr < 4; ++rr) {
                int m = mi * 16 + quad * 4 + rr;
                src[m * KA_S + ng * 32 + lrow] = f2bf(acc0[rr]);
                src[m * KA_S + ng * 32 + 16 + lrow] = f2bf(acc1[rr]);
            }
        }
        __syncthreads();

        // GRU: A-fragments register-resident; z/h weight streams rotate.
        {
            short8 aA0[13], aA1[13];
            {
                const short* ap0 = src + lrow * KA_S + quad * 8;
#pragma unroll
                for (int kk = 0; kk < 13; ++kk) {
                    aA0[kk] = *(const short8*)(ap0 + kk * 32);
                    aA1[kk] = *(const short8*)(ap0 + 16 * KA_S + kk * 32);
                }
            }
            for (int s = wave; s < 17; s += 8) {
                const short* bpr = Wrz + (s * 16 + lrow) * KFULL + quad * 8;
                const short* bpz = bpr + 272 * KFULL;
                const short* bpx = Wxn + (s * 16 + lrow) * 128 + quad * 8;
                const short* bph = Whn + (s * 16 + lrow) * KHW + quad * 8;

                short8 wr[13];
#pragma unroll
                for (int kk = 0; kk < 13; ++kk) wr[kk] = *(const short8*)(bpr + kk * 32);

                floatx4 aR0 = {}, aR1 = {}, aZ0 = {}, aZ1 = {};
                floatx4 aN0 = {}, aN1 = {}, aH0 = {}, aH1 = {};
#pragma unroll
                for (int kk = 0; kk < 13; ++kk) {           // r (+x inline); stage z
                    aR0 = MFMA(aA0[kk], wr[kk], aR0, 0, 0, 0);
                    aR1 = MFMA(aA1[kk], wr[kk], aR1, 0, 0, 0);
                    if (kk < 4) {
                        short8 bx = *(const short8*)(bpx + kk * 32);
                        aN0 = MFMA(aA0[kk], bx, aN0, 0, 0, 0);
                        aN1 = MFMA(aA1[kk], bx, aN1, 0, 0, 0);
                    }
                    wr[kk] = *(const short8*)(bpz + kk * 32);
                }
#pragma unroll
                for (int kk = 0; kk < 13; ++kk) {           // z chain; stage h
                    aZ0 = MFMA(aA0[kk], wr[kk], aZ0, 0, 0, 0);
                    aZ1 = MFMA(aA1[kk], wr[kk], aZ1, 0, 0, 0);
                    if (kk < 9) wr[kk] = *(const short8*)(bph + kk * 32);
                }
#pragma unroll
                for (int kk = 0; kk < 9; ++kk) {            // h chain
                    aH0 = MFMA(aA0[kk + 4], wr[kk], aH0, 0, 0, 0);
                    aH1 = MFMA(aA1[kk + 4], wr[kk], aH1, 0, 0, 0);
                }

                int d = s * 16 + lrow;
                if (d < D) {
                    float bgr = gb[d], bgz = gb[272 + d];
                    float bxv = gb[544 + d], bhv = gb[816 + d];
#pragma unroll
                    for (int i = 0; i < 2; ++i) {
                        floatx4 vR = i ? aR1 : aR0, vZ = i ? aZ1 : aZ0;
                        floatx4 vN = i ? aN1 : aN0, vH = i ? aH1 : aH0;
#pragma unroll
                        for (int rr = 0; rr < 4; ++rr) {
                            int m = i * 16 + quad * 4 + rr;
                            float rg = sigf(vR[rr] + bgr);
                            float zg = sigf(vZ[rr] + bgz);
                            float cg = tanh_fast(vN[rr] + bxv + rg * (vH[rr] + bhv));
                            float hold = bf2f(src[m * KA_S + 128 + d]);
                            float hv = (1.f - zg) * cg + zg * hold;
                            if (m >= nr) hv = 0.f;
                            dst[m * KA_S + 128 + d] = f2bf(hv);
                        }
                    }
                }
            }
        }
        __syncthreads();
    }

    // ---- readout: hid = relu(h2 @ Wro^T + ro_b1), h2 in bufA ----
    {
        int s = wave;
        const short* bw = Wro + (s * 16 + lrow) * KHW + quad * 8;
        short8 wv[9];
#pragma unroll
        for (int kk = 0; kk < 9; ++kk) wv[kk] = *(const short8*)(bw + kk * 32);
        floatx4 acc0 = {}, acc1 = {};
        const short* ap = bufA + lrow * KA_S + 128 + quad * 8;
#pragma unroll
        for (int kk = 0; kk < 9; ++kk) {
            short8 x0 = *(const short8*)(ap + kk * 32);
            short8 x1 = *(const short8*)(ap + 16 * KA_S + kk * 32);
            acc0 = MFMA(x0, wv[kk], acc0, 0, 0, 0);
            acc1 = MFMA(x1, wv[kk], acc1, 0, 0, 0);
        }
        int col = s * 16 + lrow;
        float bias = ro_b1g[col];
#pragma unroll
        for (int rr = 0; rr < 4; ++rr) {
            hidL[(quad * 4 + rr) * 136 + col] = f2bf(fmaxf(acc0[rr] + bias, 0.f));
            hidL[(16 + quad * 4 + rr) * 136 + col] = f2bf(fmaxf(acc1[rr] + bias, 0.f));
        }
    }
    __syncthreads();

    // ---- final: pred = hid @ ro_w2^T + ro_b2 (wave 0 only) ----
    if (wave == 0) {
        const short* bw = Wro2 + lrow * 128 + quad * 8;
        short8 wv[4];
#pragma unroll
        for (int kk = 0; kk < 4; ++kk) wv[kk] = *(const short8*)(bw + kk * 32);
        floatx4 acc0 = {}, acc1 = {};
        const short* ap = hidL + lrow * 136 + quad * 8;
#pragma unroll
        for (int kk = 0; kk < 4; ++kk) {
            short8 x0 = *(const short8*)(ap + kk * 32);
            short8 x1 = *(const short8*)(ap + 16 * 136 + kk * 32);
            acc0 = MFMA(x0, wv[kk], acc0, 0, 0, 0);
            acc1 = MFMA(x1, wv[kk], acc1, 0, 0, 0);
        }
        int q = lrow;
        if (q < NCLS) {
            float bias = ro_b2g[q];
#pragma unroll
            for (int i = 0; i < 2; ++i) {
#pragma unroll
                for (int rr = 0; rr < 4; ++rr) {
                    int m = i * 16 + quad * 4 + rr;
                    float v = (i ? acc1[rr] : acc0[rr]) + bias;
                    if (m >= nr) v = 0.f;
                    pred[((size_t)(b * 32 + m)) * NCLS + q] = v;
                }
            }
        }
    }
}

// ---------------------------------------------------------------------------
extern "C" void kernel_launch(void* const* d_in, const int* in_sizes, int n_in,
                              void* d_out, int out_size, void* d_ws, size_t ws_size,
                              hipStream_t stream)
{
    const float* nodes = (const float*)d_in[0];
    const float* pos   = (const float*)d_in[1];
    const int*   nrec  = (const int*)d_in[2];
    const float* w1    = (const float*)d_in[3];
    const float* b1    = (const float*)d_in[4];
    const float* w2    = (const float*)d_in[5];
    const float* b2    = (const float*)d_in[6];
    const float* msg_w = (const float*)d_in[7];
    const float* msg_b = (const float*)d_in[8];
    const float* w_ih  = (const float*)d_in[9];
    const float* w_hh  = (const float*)d_in[10];
    const float* b_ih  = (const float*)d_in[11];
    const float* b_hh  = (const float*)d_in[12];
    const float* ro_w1 = (const float*)d_in[13];
    const float* ro_b1 = (const float*)d_in[14];
    const float* ro_w2 = (const float*)d_in[15];
    const float* ro_b2 = (const float*)d_in[16];
    float* ws   = (float*)d_ws;
    float* pred = (float*)d_out;
    float* attout = pred + (size_t)N_G * M_N * NCLS;

    prep_kernel<<<986, 256, 0, stream>>>(w1, msg_w, w_ih, w_hh, ro_w1, ro_w2,
                                         b_ih, b_hh, b1, w2, nodes, pos, ws);
    k_proj<<<656, 256, 0, stream>>>(ws, msg_b);
    k_att<<<256, 256, 0, stream>>>(ws, nrec, b2, attout);
    k_tail<<<N_G, 512, 0, stream>>>(ws, nrec, msg_b, ro_b1, ro_b2, pred);
}

// Round 10
// 148.829 us; speedup vs baseline: 2.5992x; 1.0712x over previous
//
#include <hip/hip_runtime.h>
#include <math.h>

#define N_G   64
#define M_N   32
#define FEAT  256
#define POSD  6
#define D     262
#define MSG   128
#define NCLS  7

#define KA_S  424       // LDS buf row stride (shorts): [mv 128 | h 262 | pad]
#define KHW   288       // weight K window over h (262 -> 288)
#define KFULL 416       // full concat K
#define PSTR  320       // paL/pbL row stride (shorts)

// packed weight sizes (shorts)
#define S_PROJ (528*288)
#define S_MSG  (128*288)
#define S_RZ   (544*416)
#define S_XN   (272*128)
#define S_HN   (272*288)
#define S_RO   (128*288)
#define S_RO2  (16*128)

// workspace float offsets
#define O_WPROJ 0u
#define O_WMSG  76032u
#define O_WRZ   94464u
#define O_WXN   207616u
#define O_WHN   225024u
#define O_WRO   264192u
#define O_WRO2  282624u
#define O_GB    283648u   // 1088 fp32 gate biases [br|bz|bxn|bhn] x 272

typedef __attribute__((ext_vector_type(8))) short short8;
typedef __attribute__((ext_vector_type(4))) short short4v;
typedef __attribute__((ext_vector_type(4))) float floatx4;

#define MFMA __builtin_amdgcn_mfma_f32_16x16x32_bf16

__device__ __forceinline__ short f2bf(float f) {
    union { float f; unsigned u; } v; v.f = f;
    unsigned r = v.u + 0x7FFF + ((v.u >> 16) & 1);   // RNE
    return (short)(r >> 16);
}
__device__ __forceinline__ float bf2f(short s) {
    union { float f; unsigned u; } v;
    v.u = ((unsigned)(unsigned short)s) << 16;
    return v.f;
}
// fast sigmoid/tanh: v_exp_f32 + v_rcp_f32 (~1e-6 rel err, vs bf16-path 5e-3)
__device__ __forceinline__ float sigf(float x) {
    return __builtin_amdgcn_rcpf(1.f + __expf(-x));
}
__device__ __forceinline__ float tanh_fast(float x) {
    float e = __expf(-2.f * fabsf(x));
    float t = (1.f - e) * __builtin_amdgcn_rcpf(1.f + e);
    return copysignf(t, x);
}

// ---------------------------------------------------------------------------
// prep: ROW-PER-WAVE pack (R5 version, ~2-5us). 1892 rows, one wave each.
// ---------------------------------------------------------------------------
__global__ __launch_bounds__(256) void prep_kernel(
    const float* __restrict__ w1, const float* __restrict__ msg_w,
    const float* __restrict__ w_ih, const float* __restrict__ w_hh,
    const float* __restrict__ ro_w1, const float* __restrict__ ro_w2,
    const float* __restrict__ b_ih, const float* __restrict__ b_hh,
    float* __restrict__ ws)
{
    short* wproj = (short*)(ws + O_WPROJ);
    short* wmsg  = (short*)(ws + O_WMSG);
    short* wrz   = (short*)(ws + O_WRZ);
    short* wxn   = (short*)(ws + O_WXN);
    short* whn   = (short*)(ws + O_WHN);
    short* wro   = (short*)(ws + O_WRO);
    short* wro2  = (short*)(ws + O_WRO2);
    float* gb    = ws + O_GB;

    int row = blockIdx.x * 4 + (threadIdx.x >> 6);
    const int lane = threadIdx.x & 63;
    if (row >= 1892) return;

    if (row < 528) {                              // wproj [528][288]
        const int n = row;
        short* out = wproj + n * 288;
        const float* src = (n < D) ? (w1 + n * 524) : (w1 + (n - D) * 524 + D);
        for (int k = lane; k < 288; k += 64) {
            float v = (k < D && n < 524) ? src[k] : 0.f;
            out[k] = f2bf(v);
        }
        return;
    }
    row -= 528;
    if (row < 128) {                              // wmsg [128][288]
        const int n = row;
        short* out = wmsg + n * 288;
        const float* src = msg_w + n * D;
        for (int k = lane; k < 288; k += 64)
            out[k] = f2bf(k < D ? src[k] : 0.f);
        return;
    }
    row -= 128;
    if (row < 544) {                              // wrz [544][416]
        const int g = row;
        const int gi = (g < 272) ? 0 : 1;
        const int d = g - gi * 272;
        short* out = wrz + g * 416;
        if (d < D) {
            const int r = gi * D + d;
            const float* sih = w_ih + r * MSG;
            const float* shh = w_hh + r * D - 128;     // index by k directly
            for (int k = lane; k < 416; k += 64) {
                float v;
                if (k < 128)            v = sih[k];
                else if (k < 128 + D)   v = shh[k];
                else                    v = 0.f;
                out[k] = f2bf(v);
            }
        } else {
            for (int k = lane; k < 416; k += 64) out[k] = 0;
        }
        return;
    }
    row -= 544;
    if (row < 272) {                              // wxn [272][128]
        const int d = row;
        short* out = wxn + d * 128;
        const float* src = w_ih + (2 * D + d) * MSG;
        for (int k = lane; k < 128; k += 64)
            out[k] = f2bf(d < D ? src[k] : 0.f);
        return;
    }
    row -= 272;
    if (row < 272) {                              // whn [272][288]
        const int d = row;
        short* out = whn + d * 288;
        const float* src = w_hh + (2 * D + d) * D;
        for (int k = lane; k < 288; k += 64)
            out[k] = f2bf((d < D && k < D) ? src[k] : 0.f);
        return;
    }
    row -= 272;
    if (row < 128) {                              // wro [128][288]
        const int n = row;
        short* out = wro + n * 288;
        const float* src = ro_w1 + n * D;
        for (int k = lane; k < 288; k += 64)
            out[k] = f2bf(k < D ? src[k] : 0.f);
        return;
    }
    row -= 128;
    if (row < 16) {                               // wro2 [16][128]
        const int n = row;
        short* out = wro2 + n * 128;
        const float* src = ro_w2 + n * MSG;
        for (int k = lane; k < 128; k += 64)
            out[k] = f2bf(n < NCLS ? src[k] : 0.f);
        return;
    }
    row -= 16;
    {                                             // gate biases [4][272]
        const int seg = row;
        float* out = gb + seg * 272;
        for (int d = lane; d < 272; d += 64) {
            float v = 0.f;
            if (d < D) {
                if (seg == 0)      v = b_ih[d] + b_hh[d];
                else if (seg == 1) v = b_ih[D + d] + b_hh[D + d];
                else if (seg == 2) v = b_ih[2 * D + d];
                else               v = b_hh[2 * D + d];
            }
            out[d] = v;
        }
    }
}

// ---------------------------------------------------------------------------
// fused: one block per graph; full forward in LDS.
// Round-10: R6 structure + asm-PINNED register residency. R6/R9 counters show
// VGPR=96 despite ~200 declared live regs: the compiler rematerialized the
// "register-resident" A-fragment LDS loads inside the GRU unit loop, undoing
// the optimization. asm volatile("" : "+v"(x)) makes each staged value
// asm-defined -> rematerialization illegal -> true register residency.
// At 512 thr only 8 waves/CU are resident (2/SIMD) so VGPR 96->~230 costs
// zero real occupancy.
// ---------------------------------------------------------------------------
__global__ __launch_bounds__(512, 2) void fused_kernel(
    const float* __restrict__ nodes, const float* __restrict__ pos,
    const int* __restrict__ nrec_g,
    const float* __restrict__ b1g, const float* __restrict__ w2g,
    const float* __restrict__ b2g, const float* __restrict__ msg_bg,
    const float* __restrict__ ro_b1g, const float* __restrict__ ro_b2g,
    const float* __restrict__ ws,
    float* __restrict__ att_out, float* __restrict__ pred)
{
    const short* Wproj = (const short*)(ws + O_WPROJ);
    const short* Wmsg  = (const short*)(ws + O_WMSG);
    const short* Wrz   = (const short*)(ws + O_WRZ);
    const short* Wxn   = (const short*)(ws + O_WXN);
    const short* Whn   = (const short*)(ws + O_WHN);
    const short* Wro   = (const short*)(ws + O_WRO);
    const short* Wro2  = (const short*)(ws + O_WRO2);
    const float* gb    = ws + O_GB;

    __shared__ __align__(16) short bufA[32 * KA_S];
    __shared__ __align__(16) short bufB[32 * KA_S];
    __shared__ __align__(16) short paL[32 * PSTR];
    __shared__ __align__(16) short pbL[32 * PSTR];
    __shared__ __align__(16) short attL[32 * 40];   // bf16 A-layout for mix
    __shared__ __align__(16) short msgT[128 * 40];  // bf16 B^T layout for mix
    __shared__ __align__(16) short hidL[32 * 136];
    __shared__ __align__(16) float b1L[PSTR], w2L[PSTR];

    const int b = blockIdx.x;
    const int tid = threadIdx.x;
    const int wave = tid >> 6, lane = tid & 63;
    const int quad = lane >> 4, lrow = lane & 15;

    // ---- L2 priming: touch Wrz/Wxn/Whn (contiguous ~679 KB) early ----
    floatx4 prm[10];
    {
        const floatx4* pb = (const floatx4*)(ws + O_WRZ);
        const int base = wave * 64 + lane;
#pragma unroll
        for (int p = 0; p < 10; ++p)
            prm[p] = pb[(p * 512 + base) * 8];      // 8 floatx4 = 128 B stride
    }
    // ---- prefetch P1 tile-'wave' weights (hides under P0) ----
    short8 wvA[9];
    {
        const short* bw = Wproj + (wave * 16 + lrow) * KHW + quad * 8;
#pragma unroll
        for (int kk = 0; kk < 9; ++kk) wvA[kk] = *(const short8*)(bw + kk * 32);
    }

    const int nr = nrec_g[b];

    // ---- P0: load h0 bf16, zero pads, stage padded b1/w2 ----
    for (int idx = tid; idx < 32 * 64; idx += 512) {          // nodes (float4)
        int w = idx >> 6, c4 = idx & 63;
        floatx4 v = *(const floatx4*)(nodes + ((size_t)(b * 32 + w)) * FEAT + c4 * 4);
        short4v s; s[0] = f2bf(v[0]); s[1] = f2bf(v[1]); s[2] = f2bf(v[2]); s[3] = f2bf(v[3]);
        *(short4v*)(bufA + w * KA_S + 128 + c4 * 4) = s;
    }
    for (int idx = tid; idx < 32 * POSD; idx += 512) {        // pos
        int w = idx / POSD, c = idx % POSD;
        bufA[w * KA_S + 128 + FEAT + c] = f2bf(pos[((size_t)(b * 32 + w)) * POSD + c]);
    }
    for (int idx = tid; idx < 32 * 34; idx += 512) {          // col pads 390..423
        int w = idx / 34, c = idx % 34;
        bufA[w * KA_S + 390 + c] = 0;
        bufB[w * KA_S + 390 + c] = 0;
    }
    for (int idx = tid; idx < 32 * (PSTR - D); idx += 512) {  // pa/pb pads 262..319
        int w = idx / (PSTR - D), c = idx % (PSTR - D);
        paL[w * PSTR + D + c] = 0;
        pbL[w * PSTR + D + c] = 0;
    }
    for (int d = tid; d < PSTR; d += 512) {
        b1L[d] = (d < D) ? b1g[d] : 0.f;
        w2L[d] = (d < D) ? w2g[d] : 0.f;
    }
    // keep priming loads alive (and let their latency overlap P0's work)
#pragma unroll
    for (int p = 0; p < 10; ++p) asm volatile("" :: "v"(prm[p]));
    __syncthreads();

    // ---- P1: combined GEMM over h0 (tiles 0..32 proj, 33..40 round-0 msg) ----
    // A-fragments register-resident and asm-PINNED (18 short8 = 72 VGPR).
    {
        auto store_proj = [&](int s, floatx4 acc0, floatx4 acc1) {
            int col = s * 16 + lrow;
#pragma unroll
            for (int rr = 0; rr < 4; ++rr) {
                int r0 = quad * 4 + rr;
                if (col < D) {
                    paL[r0 * PSTR + col] = f2bf(acc0[rr]);
                    paL[(r0 + 16) * PSTR + col] = f2bf(acc1[rr]);
                } else if (col < 2 * D) {
                    pbL[r0 * PSTR + (col - D)] = f2bf(acc0[rr]);
                    pbL[(r0 + 16) * PSTR + (col - D)] = f2bf(acc1[rr]);
                }
            }
        };
        auto store_msg = [&](int s, floatx4 acc0, floatx4 acc1) {
            int col = (s - 33) * 16 + lrow;
            float bias = msg_bg[col];
#pragma unroll
            for (int rr = 0; rr < 4; ++rr) {
                msgT[col * 40 + quad * 4 + rr] = f2bf(acc0[rr] + bias);
                msgT[col * 40 + 16 + quad * 4 + rr] = f2bf(acc1[rr] + bias);
            }
        };

        short8 aF0[9], aF1[9];
        {
            const short* ap = bufA + lrow * KA_S + 128 + quad * 8;
#pragma unroll
            for (int kk = 0; kk < 9; ++kk) {
                aF0[kk] = *(const short8*)(ap + kk * 32);
                aF1[kk] = *(const short8*)(ap + 16 * KA_S + kk * 32);
            }
#pragma unroll
            for (int kk = 0; kk < 9; ++kk)
                asm volatile("" : "+v"(aF0[kk]), "+v"(aF1[kk]));
        }
        short8 wvB[9];

#define P1_LOAD(DST, TT) do { \
            const short* bw_ = ((TT) < 33) \
                ? Wproj + ((TT) * 16 + lrow) * KHW + quad * 8 \
                : Wmsg + (((TT) - 33) * 16 + lrow) * KHW + quad * 8; \
            _Pragma("unroll") \
            for (int kk = 0; kk < 9; ++kk) DST[kk] = *(const short8*)(bw_ + kk * 32); \
        } while (0)

#define P1_TILE(W, TT) do { \
            floatx4 acc0_ = {}, acc1_ = {}; \
            _Pragma("unroll") \
            for (int kk = 0; kk < 9; ++kk) { \
                acc0_ = MFMA(aF0[kk], W[kk], acc0_, 0, 0, 0); \
                acc1_ = MFMA(aF1[kk], W[kk], acc1_, 0, 0, 0); \
            } \
            if ((TT) < 33) store_proj((TT), acc0_, acc1_); \
            else store_msg((TT), acc0_, acc1_); \
        } while (0)

        int t = wave;                       // 0..7
        P1_LOAD(wvB, t + 8);                // stage next while computing current
        P1_TILE(wvA, t);
        t += 8;                             // 8..15
        P1_LOAD(wvA, t + 8);
        P1_TILE(wvB, t);
        t += 8;                             // 16..23
        P1_LOAD(wvB, t + 8);
        P1_TILE(wvA, t);
        t += 8;                             // 24..31
        P1_LOAD(wvA, t + 8);                // 32..39: always valid
        P1_TILE(wvB, t);
        t += 8;                             // 32..39
        if (t + 8 < 41) P1_LOAD(wvB, t + 8);  // only wave 0 stages tile 40
        P1_TILE(wvA, t);
        t += 8;                             // 40 for wave 0
        if (t < 41) P1_TILE(wvB, t);
#undef P1_LOAD
#undef P1_TILE
    }
    __syncthreads();

    // ---- P2: attention — 32 groups of 16 lanes, 32 j's each ----
    {
        const int grp = tid >> 4;          // i = grp (0..31)
        const int c16 = tid & 15;
        const float b2v = b2g[0];
        float pav[5][4], b1v[5][4], w2v[5][4];
#pragma unroll
        for (int k = 0; k < 5; ++k) {
            int dbase = c16 * 4 + 64 * k;
            short4v p = *(const short4v*)(paL + grp * PSTR + dbase);
            floatx4 bb = *(const floatx4*)(b1L + dbase);
            floatx4 ww = *(const floatx4*)(w2L + dbase);
#pragma unroll
            for (int e = 0; e < 4; ++e) {
                pav[k][e] = bf2f(p[e]); b1v[k][e] = bb[e]; w2v[k][e] = ww[e];
            }
        }
        // c0 = invalid-pair logit
        float p0 = 0.f;
#pragma unroll
        for (int k = 0; k < 5; ++k)
#pragma unroll
            for (int e = 0; e < 4; ++e)
                p0 += fmaxf(b1v[k][e], 0.f) * w2v[k][e];
        p0 += __shfl_down(p0, 8, 16); p0 += __shfl_down(p0, 4, 16);
        p0 += __shfl_down(p0, 2, 16); p0 += __shfl_down(p0, 1, 16);
        float c0 = sigf(p0 + b2v);
        const bool vi = grp < nr;
        for (int j = 0; j < 32; ++j) {
            float a;
            if (j < nr && vi) {
                const short* pb = pbL + j * PSTR + c16 * 4;
                float s = 0.f;
#pragma unroll
                for (int k = 0; k < 5; ++k) {
                    short4v q = *(const short4v*)(pb + 64 * k);
#pragma unroll
                    for (int e = 0; e < 4; ++e) {
                        float v = pav[k][e] + bf2f(q[e]) + b1v[k][e];
                        s += fmaxf(v, 0.f) * w2v[k][e];
                    }
                }
                s += __shfl_down(s, 8, 16); s += __shfl_down(s, 4, 16);
                s += __shfl_down(s, 2, 16); s += __shfl_down(s, 1, 16);
                a = sigf(s + b2v);
            } else {
                a = c0;
            }
            if (c16 == 0) {
                att_out[((size_t)(b * 32 + grp)) * 32 + j] = a;
                attL[grp * 40 + j] = f2bf((j < nr) ? a : 0.f);
            }
        }
    }
    __syncthreads();

    // ---- two message-passing rounds ----
    for (int rnd = 0; rnd < 2; ++rnd) {
        short* src = rnd ? bufB : bufA;
        short* dst = rnd ? bufA : bufB;

        // msg = h @ Wmsg^T + msg_b -> msgT bf16 (round 0 done in P1)
        if (rnd) {
            int s = wave;
            const short* bw = Wmsg + (s * 16 + lrow) * KHW + quad * 8;
            short8 wm[9];
#pragma unroll
            for (int kk = 0; kk < 9; ++kk) wm[kk] = *(const short8*)(bw + kk * 32);
            floatx4 acc0 = {}, acc1 = {};
            const short* ap = src + lrow * KA_S + 128 + quad * 8;
#pragma unroll
            for (int kk = 0; kk < 9; ++kk) {
                short8 x0 = *(const short8*)(ap + kk * 32);
                short8 x1 = *(const short8*)(ap + 16 * KA_S + kk * 32);
                acc0 = MFMA(x0, wm[kk], acc0, 0, 0, 0);
                acc1 = MFMA(x1, wm[kk], acc1, 0, 0, 0);
            }
            int col = s * 16 + lrow;
            float bias = msg_bg[col];
#pragma unroll
            for (int rr = 0; rr < 4; ++rr) {
                msgT[col * 40 + quad * 4 + rr] = f2bf(acc0[rr] + bias);
                msgT[col * 40 + 16 + quad * 4 + rr] = f2bf(acc1[rr] + bias);
            }
            __syncthreads();
        }

        // mix via MFMA: mv = attL(32x32) @ msg -> bf16 src cols 0..127
        {
            int mi = wave & 1, ng = wave >> 1;
            short8 afrag = *(const short8*)(attL + (mi * 16 + lrow) * 40 + quad * 8);
            floatx4 acc0 = {}, acc1 = {};
            short8 bf0 = *(const short8*)(msgT + (ng * 32 + lrow) * 40 + quad * 8);
            short8 bf1 = *(const short8*)(msgT + (ng * 32 + 16 + lrow) * 40 + quad * 8);
            acc0 = MFMA(afrag, bf0, acc0, 0, 0, 0);
            acc1 = MFMA(afrag, bf1, acc1, 0, 0, 0);
#pragma unroll
            for (int rr = 0; rr < 4; ++rr) {
                int m = mi * 16 + quad * 4 + rr;
                src[m * KA_S + ng * 32 + lrow] = f2bf(acc0[rr]);
                src[m * KA_S + ng * 32 + 16 + lrow] = f2bf(acc1[rr]);
            }
        }
        __syncthreads();

        // GRU: fused [gx|gh] GEMM + elementwise, writes dst h-cols.
        // A-fragments (26 short8 = 104 VGPR) and weight stage (13 short8 = 52)
        // asm-PINNED so the compiler cannot fold them back into LDS/global
        // reloads inside the unit loop.
        {
            short8 aA0[13], aA1[13];
            {
                const short* ap0 = src + lrow * KA_S + quad * 8;
#pragma unroll
                for (int kk = 0; kk < 13; ++kk) {
                    aA0[kk] = *(const short8*)(ap0 + kk * 32);
                    aA1[kk] = *(const short8*)(ap0 + 16 * KA_S + kk * 32);
                }
#pragma unroll
                for (int kk = 0; kk < 13; ++kk)
                    asm volatile("" : "+v"(aA0[kk]), "+v"(aA1[kk]));
            }
            for (int s = wave; s < 17; s += 8) {
                const short* bpr = Wrz + (s * 16 + lrow) * KFULL + quad * 8;
                const short* bpz = bpr + 272 * KFULL;
                const short* bpx = Wxn + (s * 16 + lrow) * 128 + quad * 8;
                const short* bph = Whn + (s * 16 + lrow) * KHW + quad * 8;

                short8 wr[13];
#pragma unroll
                for (int kk = 0; kk < 13; ++kk) wr[kk] = *(const short8*)(bpr + kk * 32);
#pragma unroll
                for (int kk = 0; kk < 13; ++kk) asm volatile("" : "+v"(wr[kk]));

                floatx4 aR0 = {}, aR1 = {}, aZ0 = {}, aZ1 = {};
                floatx4 aN0 = {}, aN1 = {}, aH0 = {}, aH1 = {};
#pragma unroll
                for (int kk = 0; kk < 13; ++kk) {           // r (+x inline); stage z
                    aR0 = MFMA(aA0[kk], wr[kk], aR0, 0, 0, 0);
                    aR1 = MFMA(aA1[kk], wr[kk], aR1, 0, 0, 0);
                    if (kk < 4) {
                        short8 bx = *(const short8*)(bpx + kk * 32);
                        aN0 = MFMA(aA0[kk], bx, aN0, 0, 0, 0);
                        aN1 = MFMA(aA1[kk], bx, aN1, 0, 0, 0);
                    }
                    wr[kk] = *(const short8*)(bpz + kk * 32);
                }
#pragma unroll
                for (int kk = 0; kk < 13; ++kk) {           // z chain; stage h
                    aZ0 = MFMA(aA0[kk], wr[kk], aZ0, 0, 0, 0);
                    aZ1 = MFMA(aA1[kk], wr[kk], aZ1, 0, 0, 0);
                    if (kk < 9) wr[kk] = *(const short8*)(bph + kk * 32);
                }
#pragma unroll
                for (int kk = 0; kk < 9; ++kk) {            // h chain
                    aH0 = MFMA(aA0[kk + 4], wr[kk], aH0, 0, 0, 0);
                    aH1 = MFMA(aA1[kk + 4], wr[kk], aH1, 0, 0, 0);
                }

                int d = s * 16 + lrow;
                if (d < D) {
                    float bgr = gb[d], bgz = gb[272 + d];
                    float bxv = gb[544 + d], bhv = gb[816 + d];
#pragma unroll
                    for (int i = 0; i < 2; ++i) {
                        floatx4 vR = i ? aR1 : aR0, vZ = i ? aZ1 : aZ0;
                        floatx4 vN = i ? aN1 : aN0, vH = i ? aH1 : aH0;
#pragma unroll
                        for (int rr = 0; rr < 4; ++rr) {
                            int m = i * 16 + quad * 4 + rr;
                            float rg = sigf(vR[rr] + bgr);
                            float zg = sigf(vZ[rr] + bgz);
                            float cg = tanh_fast(vN[rr] + bxv + rg * (vH[rr] + bhv));
                            float hold = bf2f(src[m * KA_S + 128 + d]);
                            float hv = (1.f - zg) * cg + zg * hold;
                            if (m >= nr) hv = 0.f;
                            dst[m * KA_S + 128 + d] = f2bf(hv);
                        }
                    }
                }
            }
        }
        __syncthreads();
    }

    // ---- readout: hid = relu(h2 @ Wro^T + ro_b1), h2 in bufA ----
    {
        int s = wave;
        const short* bw = Wro + (s * 16 + lrow) * KHW + quad * 8;
        short8 wv[9];
#pragma unroll
        for (int kk = 0; kk < 9; ++kk) wv[kk] = *(const short8*)(bw + kk * 32);
        floatx4 acc0 = {}, acc1 = {};
        const short* ap = bufA + lrow * KA_S + 128 + quad * 8;
#pragma unroll
        for (int kk = 0; kk < 9; ++kk) {
            short8 x0 = *(const short8*)(ap + kk * 32);
            short8 x1 = *(const short8*)(ap + 16 * KA_S + kk * 32);
            acc0 = MFMA(x0, wv[kk], acc0, 0, 0, 0);
            acc1 = MFMA(x1, wv[kk], acc1, 0, 0, 0);
        }
        int col = s * 16 + lrow;
        float bias = ro_b1g[col];
#pragma unroll
        for (int rr = 0; rr < 4; ++rr) {
            hidL[(quad * 4 + rr) * 136 + col] = f2bf(fmaxf(acc0[rr] + bias, 0.f));
            hidL[(16 + quad * 4 + rr) * 136 + col] = f2bf(fmaxf(acc1[rr] + bias, 0.f));
        }
    }
    __syncthreads();

    // ---- final: pred = hid @ ro_w2^T + ro_b2 (wave 0 only) ----
    if (wave == 0) {
        const short* bw = Wro2 + lrow * 128 + quad * 8;
        short8 wv[4];
#pragma unroll
        for (int kk = 0; kk < 4; ++kk) wv[kk] = *(const short8*)(bw + kk * 32);
        floatx4 acc0 = {}, acc1 = {};
        const short* ap = hidL + lrow * 136 + quad * 8;
#pragma unroll
        for (int kk = 0; kk < 4; ++kk) {
            short8 x0 = *(const short8*)(ap + kk * 32);
            short8 x1 = *(const short8*)(ap + 16 * 136 + kk * 32);
            acc0 = MFMA(x0, wv[kk], acc0, 0, 0, 0);
            acc1 = MFMA(x1, wv[kk], acc1, 0, 0, 0);
        }
        int q = lrow;
        if (q < NCLS) {
            float bias = ro_b2g[q];
#pragma unroll
            for (int i = 0; i < 2; ++i) {
#pragma unroll
                for (int rr = 0; rr < 4; ++rr) {
                    int m = i * 16 + quad * 4 + rr;
                    float v = (i ? acc1[rr] : acc0[rr]) + bias;
                    if (m >= nr) v = 0.f;
                    pred[((size_t)(b * 32 + m)) * NCLS + q] = v;
                }
            }
        }
    }
}

// ---------------------------------------------------------------------------
extern "C" void kernel_launch(void* const* d_in, const int* in_sizes, int n_in,
                              void* d_out, int out_size, void* d_ws, size_t ws_size,
                              hipStream_t stream)
{
    const float* nodes = (const float*)d_in[0];
    const float* pos   = (const float*)d_in[1];
    const int*   nrec  = (const int*)d_in[2];
    const float* w1    = (const float*)d_in[3];
    const float* b1    = (const float*)d_in[4];
    const float* w2    = (const float*)d_in[5];
    const float* b2    = (const float*)d_in[6];
    const float* msg_w = (const float*)d_in[7];
    const float* msg_b = (const float*)d_in[8];
    const float* w_ih  = (const float*)d_in[9];
    const float* w_hh  = (const float*)d_in[10];
    const float* b_ih  = (const float*)d_in[11];
    const float* b_hh  = (const float*)d_in[12];
    const float* ro_w1 = (const float*)d_in[13];
    const float* ro_b1 = (const float*)d_in[14];
    const float* ro_w2 = (const float*)d_in[15];
    const float* ro_b2 = (const float*)d_in[16];
    float* ws   = (float*)d_ws;
    float* pred = (float*)d_out;
    float* attout = pred + (size_t)N_G * M_N * NCLS;

    prep_kernel<<<473, 256, 0, stream>>>(w1, msg_w, w_ih, w_hh, ro_w1, ro_w2,
                                         b_ih, b_hh, ws);
    fused_kernel<<<N_G, 512, 0, stream>>>(nodes, pos, nrec, b1, w2, b2, msg_b,
                                          ro_b1, ro_b2, ws, attout, pred);
}

// Round 11
// 138.407 us; speedup vs baseline: 2.7949x; 1.0753x over previous
//
#include <hip/hip_runtime.h>
#include <math.h>

#define N_G   64
#define M_N   32
#define FEAT  256
#define POSD  6
#define D     262
#define MSG   128
#define NCLS  7

#define KA_S  424       // LDS buf row stride (shorts): [mv 128 | h 262 | pad]
#define PSTR  320       // paL/pbL row stride (shorts)

// ---------------------------------------------------------------------------
// COALESCED tile-major weight layout (R11). Old layout put adjacent lanes
// K_stride bytes apart (832B for Wrz) -> one wave load touched 64 distinct
// cache lines, 16B used of each. New layout: chunk (tile s, k-step kk, lane)
// stored contiguously -> each wave load is one 1KB fully-coalesced block.
// Slab = 512 shorts (64 lanes x 8). Region slab counts:
//   proj 33x9 | msg 8x9 | rz 2x17x13 | xn 17x4 | hn 17x9 | ro 8x9 | ro2 1x4
// Region byte sizes identical to the old layout; offsets unchanged.
// ---------------------------------------------------------------------------
#define O_WPROJ 0u
#define O_WMSG  76032u
#define O_WRZ   94464u
#define O_WXN   207616u
#define O_WHN   225024u
#define O_WRO   264192u
#define O_WRO2  282624u
#define O_GB    283648u   // 1088 fp32 gate biases [br|bz|bxn|bhn] x 272

typedef __attribute__((ext_vector_type(8))) short short8;
typedef __attribute__((ext_vector_type(4))) short short4v;
typedef __attribute__((ext_vector_type(4))) float floatx4;

#define MFMA __builtin_amdgcn_mfma_f32_16x16x32_bf16

__device__ __forceinline__ short f2bf(float f) {
    union { float f; unsigned u; } v; v.f = f;
    unsigned r = v.u + 0x7FFF + ((v.u >> 16) & 1);   // RNE
    return (short)(r >> 16);
}
__device__ __forceinline__ float bf2f(short s) {
    union { float f; unsigned u; } v;
    v.u = ((unsigned)(unsigned short)s) << 16;
    return v.f;
}
// fast sigmoid/tanh: v_exp_f32 + v_rcp_f32 (~1e-6 rel err, vs bf16-path 5e-3)
__device__ __forceinline__ float sigf(float x) {
    return __builtin_amdgcn_rcpf(1.f + __expf(-x));
}
__device__ __forceinline__ float tanh_fast(float x) {
    float e = __expf(-2.f * fabsf(x));
    float t = (1.f - e) * __builtin_amdgcn_rcpf(1.f + e);
    return copysignf(t, x);
}

// ---------------------------------------------------------------------------
// prep: SLAB-PER-WAVE pack into the coalesced tile-major layout.
// 1112 jobs: one wave writes one 512-short slab (lane writes its 8 shorts,
// gathering 8 consecutive source k's). Writes are perfectly coalesced.
// ---------------------------------------------------------------------------
__global__ __launch_bounds__(256) void prep_kernel(
    const float* __restrict__ w1, const float* __restrict__ msg_w,
    const float* __restrict__ w_ih, const float* __restrict__ w_hh,
    const float* __restrict__ ro_w1, const float* __restrict__ ro_w2,
    const float* __restrict__ b_ih, const float* __restrict__ b_hh,
    float* __restrict__ ws)
{
    short* wproj = (short*)(ws + O_WPROJ);
    short* wmsg  = (short*)(ws + O_WMSG);
    short* wrz   = (short*)(ws + O_WRZ);
    short* wxn   = (short*)(ws + O_WXN);
    short* whn   = (short*)(ws + O_WHN);
    short* wro   = (short*)(ws + O_WRO);
    short* wro2  = (short*)(ws + O_WRO2);
    float* gb    = ws + O_GB;

    int job = blockIdx.x * 4 + (threadIdx.x >> 6);
    const int lane = threadIdx.x & 63;
    if (job >= 1112) return;
    const int lrow = lane & 15, quad = lane >> 4;

    if (job < 297) {                              // proj: s 0..32, kk 0..8
        const int s = job / 9, kk = job % 9;
        const int n = s * 16 + lrow, kb = quad * 8 + kk * 32;
        short8 o;
#pragma unroll
        for (int e = 0; e < 8; ++e) {
            int k = kb + e;
            float v = 0.f;
            if (k < D && n < 524)
                v = (n < D) ? w1[n * 524 + k] : w1[(n - D) * 524 + D + k];
            o[e] = f2bf(v);
        }
        *(short8*)(wproj + job * 512 + lane * 8) = o;
        return;
    }
    job -= 297;
    if (job < 72) {                               // msg: s 0..7, kk 0..8
        const int s = job / 9, kk = job % 9;
        const int n = s * 16 + lrow, kb = quad * 8 + kk * 32;
        short8 o;
#pragma unroll
        for (int e = 0; e < 8; ++e) {
            int k = kb + e;
            o[e] = f2bf(k < D ? msg_w[n * D + k] : 0.f);
        }
        *(short8*)(wmsg + job * 512 + lane * 8) = o;
        return;
    }
    job -= 72;
    if (job < 442) {                              // rz: [r slabs 0..220][z 221..441]
        const int gi = job >= 221;
        const int jj = job - gi * 221;
        const int s = jj / 13, kk = jj % 13;
        const int d = s * 16 + lrow, kb = quad * 8 + kk * 32;
        short8 o;
#pragma unroll
        for (int e = 0; e < 8; ++e) {
            int k = kb + e;
            float v = 0.f;
            if (d < D) {
                int r = gi * D + d;
                if (k < 128)          v = w_ih[r * MSG + k];
                else if (k < 128 + D) v = w_hh[r * D + (k - 128)];
            }
            o[e] = f2bf(v);
        }
        *(short8*)(wrz + job * 512 + lane * 8) = o;
        return;
    }
    job -= 442;
    if (job < 68) {                               // xn: s 0..16, kk 0..3
        const int s = job / 4, kk = job % 4;
        const int d = s * 16 + lrow, kb = quad * 8 + kk * 32;
        short8 o;
#pragma unroll
        for (int e = 0; e < 8; ++e) {
            int k = kb + e;
            o[e] = f2bf(d < D ? w_ih[(2 * D + d) * MSG + k] : 0.f);
        }
        *(short8*)(wxn + job * 512 + lane * 8) = o;
        return;
    }
    job -= 68;
    if (job < 153) {                              // hn: s 0..16, kk 0..8
        const int s = job / 9, kk = job % 9;
        const int d = s * 16 + lrow, kb = quad * 8 + kk * 32;
        short8 o;
#pragma unroll
        for (int e = 0; e < 8; ++e) {
            int k = kb + e;
            o[e] = f2bf((d < D && k < D) ? w_hh[(2 * D + d) * D + k] : 0.f);
        }
        *(short8*)(whn + job * 512 + lane * 8) = o;
        return;
    }
    job -= 153;
    if (job < 72) {                               // ro: s 0..7, kk 0..8
        const int s = job / 9, kk = job % 9;
        const int n = s * 16 + lrow, kb = quad * 8 + kk * 32;
        short8 o;
#pragma unroll
        for (int e = 0; e < 8; ++e) {
            int k = kb + e;
            o[e] = f2bf(k < D ? ro_w1[n * D + k] : 0.f);
        }
        *(short8*)(wro + job * 512 + lane * 8) = o;
        return;
    }
    job -= 72;
    if (job < 4) {                                // ro2: kk 0..3
        const int kk = job;
        const int n = lrow, kb = quad * 8 + kk * 32;
        short8 o;
#pragma unroll
        for (int e = 0; e < 8; ++e) {
            int k = kb + e;
            o[e] = f2bf(n < NCLS ? ro_w2[n * MSG + k] : 0.f);
        }
        *(short8*)(wro2 + job * 512 + lane * 8) = o;
        return;
    }
    job -= 4;
    {                                             // gate biases [4][272]
        const int seg = job;
        float* out = gb + seg * 272;
        for (int d = lane; d < 272; d += 64) {
            float v = 0.f;
            if (d < D) {
                if (seg == 0)      v = b_ih[d] + b_hh[d];
                else if (seg == 1) v = b_ih[D + d] + b_hh[D + d];
                else if (seg == 2) v = b_ih[2 * D + d];
                else               v = b_hh[2 * D + d];
            }
            out[d] = v;
        }
    }
}

// ---------------------------------------------------------------------------
// fused: one block per graph; R10 body with COALESCED weight addressing.
// Every weight load is now base + (slab*64 + lane)*8: 64 lanes x 16B = one
// contiguous 1KB transaction (16 fully-used lines) instead of 64 quarter-used
// lines at 832B lane stride. GRU line traffic per tile drops ~4-16x.
// ---------------------------------------------------------------------------
__global__ __launch_bounds__(512, 2) void fused_kernel(
    const float* __restrict__ nodes, const float* __restrict__ pos,
    const int* __restrict__ nrec_g,
    const float* __restrict__ b1g, const float* __restrict__ w2g,
    const float* __restrict__ b2g, const float* __restrict__ msg_bg,
    const float* __restrict__ ro_b1g, const float* __restrict__ ro_b2g,
    const float* __restrict__ ws,
    float* __restrict__ att_out, float* __restrict__ pred)
{
    const short* Wproj = (const short*)(ws + O_WPROJ);
    const short* Wmsg  = (const short*)(ws + O_WMSG);
    const short* Wrz   = (const short*)(ws + O_WRZ);
    const short* Wxn   = (const short*)(ws + O_WXN);
    const short* Whn   = (const short*)(ws + O_WHN);
    const short* Wro   = (const short*)(ws + O_WRO);
    const short* Wro2  = (const short*)(ws + O_WRO2);
    const float* gb    = ws + O_GB;

    __shared__ __align__(16) short bufA[32 * KA_S];
    __shared__ __align__(16) short bufB[32 * KA_S];
    __shared__ __align__(16) short paL[32 * PSTR];
    __shared__ __align__(16) short pbL[32 * PSTR];
    __shared__ __align__(16) short attL[32 * 40];   // bf16 A-layout for mix
    __shared__ __align__(16) short msgT[128 * 40];  // bf16 B^T layout for mix
    __shared__ __align__(16) short hidL[32 * 136];
    __shared__ __align__(16) float b1L[PSTR], w2L[PSTR];

    const int b = blockIdx.x;
    const int tid = threadIdx.x;
    const int wave = tid >> 6, lane = tid & 63;
    const int quad = lane >> 4, lrow = lane & 15;

    // ---- L2 priming: touch Wrz/Wxn/Whn (contiguous ~679 KB) early ----
    floatx4 prm[10];
    {
        const floatx4* pb = (const floatx4*)(ws + O_WRZ);
        const int base = wave * 64 + lane;
#pragma unroll
        for (int p = 0; p < 10; ++p)
            prm[p] = pb[(p * 512 + base) * 8];      // 8 floatx4 = 128 B stride
    }
    // ---- prefetch P1 tile-'wave' weights (hides under P0) ----
    short8 wvA[9];
    {
        const short* bw = Wproj + wave * 9 * 512 + lane * 8;
#pragma unroll
        for (int kk = 0; kk < 9; ++kk) wvA[kk] = *(const short8*)(bw + kk * 512);
    }

    const int nr = nrec_g[b];

    // ---- P0: load h0 bf16, zero pads, stage padded b1/w2 ----
    for (int idx = tid; idx < 32 * 64; idx += 512) {          // nodes (float4)
        int w = idx >> 6, c4 = idx & 63;
        floatx4 v = *(const floatx4*)(nodes + ((size_t)(b * 32 + w)) * FEAT + c4 * 4);
        short4v s; s[0] = f2bf(v[0]); s[1] = f2bf(v[1]); s[2] = f2bf(v[2]); s[3] = f2bf(v[3]);
        *(short4v*)(bufA + w * KA_S + 128 + c4 * 4) = s;
    }
    for (int idx = tid; idx < 32 * POSD; idx += 512) {        // pos
        int w = idx / POSD, c = idx % POSD;
        bufA[w * KA_S + 128 + FEAT + c] = f2bf(pos[((size_t)(b * 32 + w)) * POSD + c]);
    }
    for (int idx = tid; idx < 32 * 34; idx += 512) {          // col pads 390..423
        int w = idx / 34, c = idx % 34;
        bufA[w * KA_S + 390 + c] = 0;
        bufB[w * KA_S + 390 + c] = 0;
    }
    for (int idx = tid; idx < 32 * (PSTR - D); idx += 512) {  // pa/pb pads 262..319
        int w = idx / (PSTR - D), c = idx % (PSTR - D);
        paL[w * PSTR + D + c] = 0;
        pbL[w * PSTR + D + c] = 0;
    }
    for (int d = tid; d < PSTR; d += 512) {
        b1L[d] = (d < D) ? b1g[d] : 0.f;
        w2L[d] = (d < D) ? w2g[d] : 0.f;
    }
    // keep priming loads alive (and let their latency overlap P0's work)
#pragma unroll
    for (int p = 0; p < 10; ++p) asm volatile("" :: "v"(prm[p]));
    __syncthreads();

    // ---- P1: combined GEMM over h0 (tiles 0..32 proj, 33..40 round-0 msg) ----
    {
        auto store_proj = [&](int s, floatx4 acc0, floatx4 acc1) {
            int col = s * 16 + lrow;
#pragma unroll
            for (int rr = 0; rr < 4; ++rr) {
                int r0 = quad * 4 + rr;
                if (col < D) {
                    paL[r0 * PSTR + col] = f2bf(acc0[rr]);
                    paL[(r0 + 16) * PSTR + col] = f2bf(acc1[rr]);
                } else if (col < 2 * D) {
                    pbL[r0 * PSTR + (col - D)] = f2bf(acc0[rr]);
                    pbL[(r0 + 16) * PSTR + (col - D)] = f2bf(acc1[rr]);
                }
            }
        };
        auto store_msg = [&](int s, floatx4 acc0, floatx4 acc1) {
            int col = (s - 33) * 16 + lrow;
            float bias = msg_bg[col];
#pragma unroll
            for (int rr = 0; rr < 4; ++rr) {
                msgT[col * 40 + quad * 4 + rr] = f2bf(acc0[rr] + bias);
                msgT[col * 40 + 16 + quad * 4 + rr] = f2bf(acc1[rr] + bias);
            }
        };

        short8 aF0[9], aF1[9];
        {
            const short* ap = bufA + lrow * KA_S + 128 + quad * 8;
#pragma unroll
            for (int kk = 0; kk < 9; ++kk) {
                aF0[kk] = *(const short8*)(ap + kk * 32);
                aF1[kk] = *(const short8*)(ap + 16 * KA_S + kk * 32);
            }
#pragma unroll
            for (int kk = 0; kk < 9; ++kk)
                asm volatile("" : "+v"(aF0[kk]), "+v"(aF1[kk]));
        }
        short8 wvB[9];

#define P1_LOAD(DST, TT) do { \
            const short* bw_ = ((TT) < 33) \
                ? Wproj + (TT) * 9 * 512 + lane * 8 \
                : Wmsg + ((TT) - 33) * 9 * 512 + lane * 8; \
            _Pragma("unroll") \
            for (int kk = 0; kk < 9; ++kk) DST[kk] = *(const short8*)(bw_ + kk * 512); \
        } while (0)

#define P1_TILE(W, TT) do { \
            floatx4 acc0_ = {}, acc1_ = {}; \
            _Pragma("unroll") \
            for (int kk = 0; kk < 9; ++kk) { \
                acc0_ = MFMA(aF0[kk], W[kk], acc0_, 0, 0, 0); \
                acc1_ = MFMA(aF1[kk], W[kk], acc1_, 0, 0, 0); \
            } \
            if ((TT) < 33) store_proj((TT), acc0_, acc1_); \
            else store_msg((TT), acc0_, acc1_); \
        } while (0)

        int t = wave;                       // 0..7
        P1_LOAD(wvB, t + 8);                // stage next while computing current
        P1_TILE(wvA, t);
        t += 8;                             // 8..15
        P1_LOAD(wvA, t + 8);
        P1_TILE(wvB, t);
        t += 8;                             // 16..23
        P1_LOAD(wvB, t + 8);
        P1_TILE(wvA, t);
        t += 8;                             // 24..31
        P1_LOAD(wvA, t + 8);                // 32..39: always valid
        P1_TILE(wvB, t);
        t += 8;                             // 32..39
        if (t + 8 < 41) P1_LOAD(wvB, t + 8);  // only wave 0 stages tile 40
        P1_TILE(wvA, t);
        t += 8;                             // 40 for wave 0
        if (t < 41) P1_TILE(wvB, t);
#undef P1_LOAD
#undef P1_TILE
    }
    __syncthreads();

    // ---- P2: attention — 32 groups of 16 lanes, 32 j's each ----
    {
        const int grp = tid >> 4;          // i = grp (0..31)
        const int c16 = tid & 15;
        const float b2v = b2g[0];
        float pav[5][4], b1v[5][4], w2v[5][4];
#pragma unroll
        for (int k = 0; k < 5; ++k) {
            int dbase = c16 * 4 + 64 * k;
            short4v p = *(const short4v*)(paL + grp * PSTR + dbase);
            floatx4 bb = *(const floatx4*)(b1L + dbase);
            floatx4 ww = *(const floatx4*)(w2L + dbase);
#pragma unroll
            for (int e = 0; e < 4; ++e) {
                pav[k][e] = bf2f(p[e]); b1v[k][e] = bb[e]; w2v[k][e] = ww[e];
            }
        }
        // c0 = invalid-pair logit
        float p0 = 0.f;
#pragma unroll
        for (int k = 0; k < 5; ++k)
#pragma unroll
            for (int e = 0; e < 4; ++e)
                p0 += fmaxf(b1v[k][e], 0.f) * w2v[k][e];
        p0 += __shfl_down(p0, 8, 16); p0 += __shfl_down(p0, 4, 16);
        p0 += __shfl_down(p0, 2, 16); p0 += __shfl_down(p0, 1, 16);
        float c0 = sigf(p0 + b2v);
        const bool vi = grp < nr;
        for (int j = 0; j < 32; ++j) {
            float a;
            if (j < nr && vi) {
                const short* pb = pbL + j * PSTR + c16 * 4;
                float s = 0.f;
#pragma unroll
                for (int k = 0; k < 5; ++k) {
                    short4v q = *(const short4v*)(pb + 64 * k);
#pragma unroll
                    for (int e = 0; e < 4; ++e) {
                        float v = pav[k][e] + bf2f(q[e]) + b1v[k][e];
                        s += fmaxf(v, 0.f) * w2v[k][e];
                    }
                }
                s += __shfl_down(s, 8, 16); s += __shfl_down(s, 4, 16);
                s += __shfl_down(s, 2, 16); s += __shfl_down(s, 1, 16);
                a = sigf(s + b2v);
            } else {
                a = c0;
            }
            if (c16 == 0) {
                att_out[((size_t)(b * 32 + grp)) * 32 + j] = a;
                attL[grp * 40 + j] = f2bf((j < nr) ? a : 0.f);
            }
        }
    }
    __syncthreads();

    // ---- two message-passing rounds ----
    for (int rnd = 0; rnd < 2; ++rnd) {
        short* src = rnd ? bufB : bufA;
        short* dst = rnd ? bufA : bufB;

        // msg = h @ Wmsg^T + msg_b -> msgT bf16 (round 0 done in P1)
        if (rnd) {
            int s = wave;
            const short* bw = Wmsg + s * 9 * 512 + lane * 8;
            short8 wm[9];
#pragma unroll
            for (int kk = 0; kk < 9; ++kk) wm[kk] = *(const short8*)(bw + kk * 512);
            floatx4 acc0 = {}, acc1 = {};
            const short* ap = src + lrow * KA_S + 128 + quad * 8;
#pragma unroll
            for (int kk = 0; kk < 9; ++kk) {
                short8 x0 = *(const short8*)(ap + kk * 32);
                short8 x1 = *(const short8*)(ap + 16 * KA_S + kk * 32);
                acc0 = MFMA(x0, wm[kk], acc0, 0, 0, 0);
                acc1 = MFMA(x1, wm[kk], acc1, 0, 0, 0);
            }
            int col = s * 16 + lrow;
            float bias = msg_bg[col];
#pragma unroll
            for (int rr = 0; rr < 4; ++rr) {
                msgT[col * 40 + quad * 4 + rr] = f2bf(acc0[rr] + bias);
                msgT[col * 40 + 16 + quad * 4 + rr] = f2bf(acc1[rr] + bias);
            }
            __syncthreads();
        }

        // mix via MFMA: mv = attL(32x32) @ msg -> bf16 src cols 0..127
        {
            int mi = wave & 1, ng = wave >> 1;
            short8 afrag = *(const short8*)(attL + (mi * 16 + lrow) * 40 + quad * 8);
            floatx4 acc0 = {}, acc1 = {};
            short8 bf0 = *(const short8*)(msgT + (ng * 32 + lrow) * 40 + quad * 8);
            short8 bf1 = *(const short8*)(msgT + (ng * 32 + 16 + lrow) * 40 + quad * 8);
            acc0 = MFMA(afrag, bf0, acc0, 0, 0, 0);
            acc1 = MFMA(afrag, bf1, acc1, 0, 0, 0);
#pragma unroll
            for (int rr = 0; rr < 4; ++rr) {
                int m = mi * 16 + quad * 4 + rr;
                src[m * KA_S + ng * 32 + lrow] = f2bf(acc0[rr]);
                src[m * KA_S + ng * 32 + 16 + lrow] = f2bf(acc1[rr]);
            }
        }
        __syncthreads();

        // GRU: fused [gx|gh] GEMM + elementwise, writes dst h-cols.
        // Weight loads now fully coalesced: chunk (s,kk,lane) contiguous.
        {
            short8 aA0[13], aA1[13];
            {
                const short* ap0 = src + lrow * KA_S + quad * 8;
#pragma unroll
                for (int kk = 0; kk < 13; ++kk) {
                    aA0[kk] = *(const short8*)(ap0 + kk * 32);
                    aA1[kk] = *(const short8*)(ap0 + 16 * KA_S + kk * 32);
                }
#pragma unroll
                for (int kk = 0; kk < 13; ++kk)
                    asm volatile("" : "+v"(aA0[kk]), "+v"(aA1[kk]));
            }
            for (int s = wave; s < 17; s += 8) {
                const short* bpr = Wrz + (s * 13) * 512 + lane * 8;
                const short* bpz = Wrz + (221 + s * 13) * 512 + lane * 8;
                const short* bpx = Wxn + (s * 4) * 512 + lane * 8;
                const short* bph = Whn + (s * 9) * 512 + lane * 8;

                short8 wr[13];
#pragma unroll
                for (int kk = 0; kk < 13; ++kk) wr[kk] = *(const short8*)(bpr + kk * 512);
#pragma unroll
                for (int kk = 0; kk < 13; ++kk) asm volatile("" : "+v"(wr[kk]));

                floatx4 aR0 = {}, aR1 = {}, aZ0 = {}, aZ1 = {};
                floatx4 aN0 = {}, aN1 = {}, aH0 = {}, aH1 = {};
#pragma unroll
                for (int kk = 0; kk < 13; ++kk) {           // r (+x inline); stage z
                    aR0 = MFMA(aA0[kk], wr[kk], aR0, 0, 0, 0);
                    aR1 = MFMA(aA1[kk], wr[kk], aR1, 0, 0, 0);
                    if (kk < 4) {
                        short8 bx = *(const short8*)(bpx + kk * 512);
                        aN0 = MFMA(aA0[kk], bx, aN0, 0, 0, 0);
                        aN1 = MFMA(aA1[kk], bx, aN1, 0, 0, 0);
                    }
                    wr[kk] = *(const short8*)(bpz + kk * 512);
                }
#pragma unroll
                for (int kk = 0; kk < 13; ++kk) {           // z chain; stage h
                    aZ0 = MFMA(aA0[kk], wr[kk], aZ0, 0, 0, 0);
                    aZ1 = MFMA(aA1[kk], wr[kk], aZ1, 0, 0, 0);
                    if (kk < 9) wr[kk] = *(const short8*)(bph + kk * 512);
                }
#pragma unroll
                for (int kk = 0; kk < 9; ++kk) {            // h chain
                    aH0 = MFMA(aA0[kk + 4], wr[kk], aH0, 0, 0, 0);
                    aH1 = MFMA(aA1[kk + 4], wr[kk], aH1, 0, 0, 0);
                }

                int d = s * 16 + lrow;
                if (d < D) {
                    float bgr = gb[d], bgz = gb[272 + d];
                    float bxv = gb[544 + d], bhv = gb[816 + d];
#pragma unroll
                    for (int i = 0; i < 2; ++i) {
                        floatx4 vR = i ? aR1 : aR0, vZ = i ? aZ1 : aZ0;
                        floatx4 vN = i ? aN1 : aN0, vH = i ? aH1 : aH0;
#pragma unroll
                        for (int rr = 0; rr < 4; ++rr) {
                            int m = i * 16 + quad * 4 + rr;
                            float rg = sigf(vR[rr] + bgr);
                            float zg = sigf(vZ[rr] + bgz);
                            float cg = tanh_fast(vN[rr] + bxv + rg * (vH[rr] + bhv));
                            float hold = bf2f(src[m * KA_S + 128 + d]);
                            float hv = (1.f - zg) * cg + zg * hold;
                            if (m >= nr) hv = 0.f;
                            dst[m * KA_S + 128 + d] = f2bf(hv);
                        }
                    }
                }
            }
        }
        __syncthreads();
    }

    // ---- readout: hid = relu(h2 @ Wro^T + ro_b1), h2 in bufA ----
    {
        int s = wave;
        const short* bw = Wro + s * 9 * 512 + lane * 8;
        short8 wv[9];
#pragma unroll
        for (int kk = 0; kk < 9; ++kk) wv[kk] = *(const short8*)(bw + kk * 512);
        floatx4 acc0 = {}, acc1 = {};
        const short* ap = bufA + lrow * KA_S + 128 + quad * 8;
#pragma unroll
        for (int kk = 0; kk < 9; ++kk) {
            short8 x0 = *(const short8*)(ap + kk * 32);
            short8 x1 = *(const short8*)(ap + 16 * KA_S + kk * 32);
            acc0 = MFMA(x0, wv[kk], acc0, 0, 0, 0);
            acc1 = MFMA(x1, wv[kk], acc1, 0, 0, 0);
        }
        int col = s * 16 + lrow;
        float bias = ro_b1g[col];
#pragma unroll
        for (int rr = 0; rr < 4; ++rr) {
            hidL[(quad * 4 + rr) * 136 + col] = f2bf(fmaxf(acc0[rr] + bias, 0.f));
            hidL[(16 + quad * 4 + rr) * 136 + col] = f2bf(fmaxf(acc1[rr] + bias, 0.f));
        }
    }
    __syncthreads();

    // ---- final: pred = hid @ ro_w2^T + ro_b2 (wave 0 only) ----
    if (wave == 0) {
        const short* bw = Wro2 + lane * 8;
        short8 wv[4];
#pragma unroll
        for (int kk = 0; kk < 4; ++kk) wv[kk] = *(const short8*)(bw + kk * 512);
        floatx4 acc0 = {}, acc1 = {};
        const short* ap = hidL + lrow * 136 + quad * 8;
#pragma unroll
        for (int kk = 0; kk < 4; ++kk) {
            short8 x0 = *(const short8*)(ap + kk * 32);
            short8 x1 = *(const short8*)(ap + 16 * 136 + kk * 32);
            acc0 = MFMA(x0, wv[kk], acc0, 0, 0, 0);
            acc1 = MFMA(x1, wv[kk], acc1, 0, 0, 0);
        }
        int q = lrow;
        if (q < NCLS) {
            float bias = ro_b2g[q];
#pragma unroll
            for (int i = 0; i < 2; ++i) {
#pragma unroll
                for (int rr = 0; rr < 4; ++rr) {
                    int m = i * 16 + quad * 4 + rr;
                    float v = (i ? acc1[rr] : acc0[rr]) + bias;
                    if (m >= nr) v = 0.f;
                    pred[((size_t)(b * 32 + m)) * NCLS + q] = v;
                }
            }
        }
    }
}

// ---------------------------------------------------------------------------
extern "C" void kernel_launch(void* const* d_in, const int* in_sizes, int n_in,
                              void* d_out, int out_size, void* d_ws, size_t ws_size,
                              hipStream_t stream)
{
    const float* nodes = (const float*)d_in[0];
    const float* pos   = (const float*)d_in[1];
    const int*   nrec  = (const int*)d_in[2];
    const float* w1    = (const float*)d_in[3];
    const float* b1    = (const float*)d_in[4];
    const float* w2    = (const float*)d_in[5];
    const float* b2    = (const float*)d_in[6];
    const float* msg_w = (const float*)d_in[7];
    const float* msg_b = (const float*)d_in[8];
    const float* w_ih  = (const float*)d_in[9];
    const float* w_hh  = (const float*)d_in[10];
    const float* b_ih  = (const float*)d_in[11];
    const float* b_hh  = (const float*)d_in[12];
    const float* ro_w1 = (const float*)d_in[13];
    const float* ro_b1 = (const float*)d_in[14];
    const float* ro_w2 = (const float*)d_in[15];
    const float* ro_b2 = (const float*)d_in[16];
    float* ws   = (float*)d_ws;
    float* pred = (float*)d_out;
    float* attout = pred + (size_t)N_G * M_N * NCLS;

    prep_kernel<<<278, 256, 0, stream>>>(w1, msg_w, w_ih, w_hh, ro_w1, ro_w2,
                                         b_ih, b_hh, ws);
    fused_kernel<<<N_G, 512, 0, stream>>>(nodes, pos, nrec, b1, w2, b2, msg_b,
                                          ro_b1, ro_b2, ws, attout, pred);
}